// Round 5
// baseline (5842.429 us; speedup 1.0000x reference)
//
#include <hip/hip_runtime.h>
#include <cstdint>
#include <cstddef>

#define N_NODES 100000
#define D 64
#define NNZ 3200000
#define BB 64
#define LL 200
#define BSHIFT 7
#define BSIZE 128               // nodes per bucket
#define NBUCK 782               // ceil(100000/128)
#define CAP 4608                // max edges per bucket (avg 4092, +8 sigma)
#define BM_WORDS 3200           // >= ceil(100000/32)

// ---------------------------------------------------------------- utilities
__device__ __forceinline__ float wave_sum(float x) {
#pragma unroll
  for (int o = 32; o; o >>= 1) x += __shfl_xor(x, o, 64);
  return x;
}

// ---------------------------------------------------------------- mark rows needed by output
__global__ void mark_kernel(const int* __restrict__ input, uint32_t* __restrict__ bm) {
  int t = blockIdx.x * 256 + threadIdx.x;
  if (t < BB * LL) {
    int i = input[t];
    atomicOr(&bm[i >> 5], 1u << (i & 31));
  }
}

// ---------------------------------------------------------------- gate: e2 = u*sigmoid(u@w0+b0), e3 likewise
__global__ __launch_bounds__(256) void gate_kernel(
    const float* __restrict__ u, const float* __restrict__ w0,
    const float* __restrict__ w1, const float* __restrict__ b0,
    const float* __restrict__ b1, float* __restrict__ e2, float* __restrict__ e3) {
  __shared__ float sw0[D * D];
  __shared__ float sw1[D * D];
  __shared__ float sb0[D], sb1[D];
  for (int t = threadIdx.x; t < D * D; t += 256) { sw0[t] = w0[t]; sw1[t] = w1[t]; }
  if (threadIdx.x < D) { sb0[threadIdx.x] = b0[threadIdx.x]; sb1[threadIdx.x] = b1[threadIdx.x]; }
  __syncthreads();
  int wave = (blockIdx.x * 256 + threadIdx.x) >> 6;
  int lane = threadIdx.x & 63;
  int nw = (gridDim.x * 256) >> 6;
  for (int i = wave; i < N_NODES; i += nw) {
    float uv = u[i * D + lane];
    float a0 = 0.f, a1 = 0.f;
#pragma unroll
    for (int k = 0; k < D; ++k) {
      float uk = __shfl(uv, k, 64);
      a0 = fmaf(uk, sw0[k * D + lane], a0);
      a1 = fmaf(uk, sw1[k * D + lane], a1);
    }
    a0 += sb0[lane];
    a1 += sb1[lane];
    float s0 = 1.f / (1.f + expf(-a0));
    float s1 = 1.f / (1.f + expf(-a1));
    e2[i * D + lane] = uv * s0;
    e3[i * D + lane] = uv * s1;
  }
}

// ---------------------------------------------------------------- bucket binning
__global__ void init_cursor_kernel(uint32_t* __restrict__ gcursor) {
  int t = blockIdx.x * 256 + threadIdx.x;
  if (t < NBUCK) gcursor[t] = (uint32_t)t * CAP;
}

// chunk of 8192 edges per block; per-block LDS histogram -> one global atomic
// per present bucket -> direct positioned writes (bursts within buckets).
__global__ __launch_bounds__(1024) void bin_kernel(
    const int* __restrict__ dsts, const int* __restrict__ srcs,
    const float* __restrict__ val, uint32_t* __restrict__ gcursor,
    uint2* __restrict__ binned) {
  __shared__ uint32_t hist[NBUCK];
  __shared__ uint32_t gbase[NBUCK];
  const int CHUNK = 8192;
  int base = blockIdx.x * CHUNK;
  int tid = threadIdx.x;
  for (int t = tid; t < NBUCK; t += 1024) hist[t] = 0u;
  __syncthreads();
  int n = NNZ - base;
  if (n > CHUNK) n = CHUNK;
  uint32_t px[8]; float pv[8]; uint32_t pb[8]; uint32_t pr[8];
#pragma unroll
  for (int k = 0; k < 8; ++k) {
    int off = (k << 10) + tid;
    bool ok = off < n;
    int e = base + off;
    int d = ok ? dsts[e] : 0;
    int s = ok ? srcs[e] : 0;
    float v = ok ? val[e] : 0.f;
    uint32_t b = (uint32_t)d >> BSHIFT;
    pb[k] = ok ? b : 0xFFFFFFFFu;
    pr[k] = ok ? atomicAdd(&hist[b], 1u) : 0u;
    px[k] = (uint32_t)s | ((uint32_t)(d & (BSIZE - 1)) << 17);
    pv[k] = v;
  }
  __syncthreads();
  for (int t = tid; t < NBUCK; t += 1024) {
    uint32_t h = hist[t];
    gbase[t] = h ? atomicAdd(&gcursor[t], h) : 0u;
  }
  __syncthreads();
#pragma unroll
  for (int k = 0; k < 8; ++k) {
    if (pb[k] != 0xFFFFFFFFu) {
      uint32_t pos = gbase[pb[k]] + pr[k];
      uint32_t lim = (pb[k] + 1u) * CAP;
      if (pos < lim) {  // overflow guard: never corrupt the next bucket
        binned[pos] = make_uint2(px[k], __float_as_uint(pv[k]));
      }
    }
  }
}

// ---------------------------------------------------------------- bucket spmm
// one block per bucket; LDS accumulator acc[128][65] (pad -> ~2-way ds conflicts);
// 4 edges per quad-iteration, float4 gather per 16-lane group (proven structure).
template <bool FILTER>
__global__ __launch_bounds__(512) void bucket_spmm_kernel(
    const uint32_t* __restrict__ gcursor, const uint2* __restrict__ binned,
    const float* __restrict__ xin, float* __restrict__ xout,
    const uint32_t* __restrict__ bitmap) {
  __shared__ float acc[BSIZE * 65];
  __shared__ uint32_t rmask[BSIZE / 32];
  int bucket = blockIdx.x;
  int tid = threadIdx.x;
  int nodebase = bucket << BSHIFT;
  for (int t = tid; t < BSIZE * 65; t += 512) acc[t] = 0.f;
  if (tid < BSIZE / 32) {
    rmask[tid] = FILTER ? bitmap[(nodebase >> 5) + tid] : 0xFFFFFFFFu;
  }
  __syncthreads();
  uint32_t cnt = gcursor[bucket] - (uint32_t)bucket * CAP;
  if (cnt > CAP) cnt = CAP;
  const uint2* ep = binned + (size_t)bucket * CAP;
  int wave = tid >> 6, lane = tid & 63;
  int g = lane >> 4, c = lane & 15;
  int ntiles = ((int)cnt + 63) >> 6;
  for (int t = wave; t < ntiles; t += 8) {
    int ei = (t << 6) + lane;
    uint2 p = make_uint2(0u, 0u);
    if (ei < (int)cnt) p = ep[ei];
#pragma unroll
    for (int q = 0; q < 16; ++q) {
      int e = (q << 2) + g;
      uint32_t x = (uint32_t)__shfl((int)p.x, e, 64);
      float v = __uint_as_float((uint32_t)__shfl((int)p.y, e, 64));
      uint32_t src = x & 0x1FFFFu;
      uint32_t ldst = x >> 17;
      if (FILTER) {
        if (!((rmask[ldst >> 5] >> (ldst & 31)) & 1u)) { src = 0u; v = 0.f; }
      }
      float4 xv = ((const float4*)(xin + (size_t)src * D))[c];
      float* ap = &acc[ldst * 65 + (c << 2)];
      atomicAdd(ap + 0, v * xv.x);
      atomicAdd(ap + 1, v * xv.y);
      atomicAdd(ap + 2, v * xv.z);
      atomicAdd(ap + 3, v * xv.w);
    }
  }
  __syncthreads();
  int nvalid = N_NODES - nodebase;
  if (nvalid > BSIZE) nvalid = BSIZE;
  for (int idx = tid; idx < (nvalid << 6); idx += 512) {
    int r = idx >> 6, cc = idx & 63;
    if (FILTER) {
      if (!((rmask[r >> 5] >> (r & 31)) & 1u)) continue;
    }
    xout[(size_t)(nodebase + r) * D + cc] = acc[r * 65 + cc];
  }
}

// ---------------------------------------------------------------- final: fused acc/l2norm/mix + seq attention
__global__ __launch_bounds__(256) void final_kernel(
    const int* __restrict__ input,
    const float* __restrict__ e20, const float* __restrict__ e21, const float* __restrict__ e22,
    const float* __restrict__ e30, const float* __restrict__ e31, const float* __restrict__ e32,
    const float* __restrict__ att, const float* __restrict__ att_m,
    float* __restrict__ out_Lcas, float* __restrict__ out_cas) {
  __shared__ float cas[LL * D];  // 51.2 KB
  __shared__ float sv[D];
  __shared__ float sscore[LL];
  __shared__ float red[8];
  int b = blockIdx.x, tid = threadIdx.x;
  if (tid < D) {
    float a = 0.f;
#pragma unroll
    for (int j = 0; j < D; ++j) a = fmaf(att_m[tid * D + j], att[j], a);
    sv[tid] = a;
  }
  __syncthreads();
  int wv = tid >> 6, lane = tid & 63;
  float svl = sv[lane];
  for (int l = wv; l < LL; l += 4) {
    int i = input[b * LL + l];
    size_t o = (size_t)i * D + lane;
    float v20 = e20[o], v21 = e21[o], v22 = e22[o];
    float v30 = e30[o], v31 = e31[o], v32 = e32[o];
    float n21 = fmaxf(sqrtf(wave_sum(v21 * v21)), 1e-12f);
    float n22 = fmaxf(sqrtf(wave_sum(v22 * v22)), 1e-12f);
    float n31 = fmaxf(sqrtf(wave_sum(v31 * v31)), 1e-12f);
    float n32 = fmaxf(sqrtf(wave_sum(v32 * v32)), 1e-12f);
    float a2 = v20 + v21 / n21 + v22 / n22;
    float a3 = v30 + v31 / n31 + v32 / n32;
    float w2 = wave_sum(a2 * svl);
    float w3 = wave_sum(a3 * svl);
    float mx = fmaxf(w2, w3);
    float ex2 = expf(w2 - mx), ex3 = expf(w3 - mx);
    float inv = 1.f / (ex2 + ex3);
    float mix = (ex2 * a2 + ex3 * a3) * inv;
    cas[l * D + lane] = mix;
    out_cas[(size_t)(b * LL + l) * D + lane] = mix;
  }
  __syncthreads();
  for (int l = wv; l < LL; l += 4) {
    float s = wave_sum(cas[lane] * cas[l * D + lane]) * 0.125f;  // 1/sqrt(64)
    int iv = input[b * LL + l];
    s = (iv == 0) ? -1e9f : s;
    if (lane == 0) sscore[l] = s;
  }
  __syncthreads();
  float m = -INFINITY;
  for (int l = tid; l < LL; l += 256) m = fmaxf(m, sscore[l]);
#pragma unroll
  for (int o = 32; o; o >>= 1) m = fmaxf(m, __shfl_xor(m, o, 64));
  if (lane == 0) red[wv] = m;
  __syncthreads();
  m = fmaxf(fmaxf(red[0], red[1]), fmaxf(red[2], red[3]));
  float sum = 0.f;
  for (int l = tid; l < LL; l += 256) sum += expf(sscore[l] - m);
  sum = wave_sum(sum);
  if (lane == 0) red[4 + wv] = sum;
  __syncthreads();
  float inv = 1.f / (red[4] + red[5] + red[6] + red[7]);
  for (int l = tid; l < LL; l += 256) sscore[l] = expf(sscore[l] - m) * inv;
  __syncthreads();
  for (int t = tid; t < LL * D; t += 256)
    out_Lcas[(size_t)b * LL * D + t] = sscore[t >> 6] * cas[t];
}

// ---------------------------------------------------------------- launch
extern "C" void kernel_launch(void* const* d_in, const int* in_sizes, int n_in,
                              void* d_out, int out_size, void* d_ws, size_t ws_size,
                              hipStream_t stream) {
  const int* input = (const int*)d_in[0];
  const int* h_item_idx = (const int*)d_in[1];
  const float* h_item_val = (const float*)d_in[2];
  const int* h_user_idx = (const int*)d_in[3];
  const float* h_user_val = (const float*)d_in[4];
  const float* user_emb = (const float*)d_in[5];
  const float* w0 = (const float*)d_in[6];
  const float* w1 = (const float*)d_in[7];
  const float* b0 = (const float*)d_in[8];
  const float* b1 = (const float*)d_in[9];
  const float* att = (const float*)d_in[10];
  const float* att_m = (const float*)d_in[11];

  float* out = (float*)d_out;
  float* out_Lcas = out;                       // B*L*D
  float* out_cas = out + (size_t)BB * LL * D;  // B*L*D

  const size_t ND = (size_t)N_NODES * D;  // 6.4M floats
  char* ws = (char*)d_ws;
  float* e20 = (float*)ws; ws += ND * 4;
  float* e30 = (float*)ws; ws += ND * 4;
  float* e21 = (float*)ws; ws += ND * 4;
  float* e31 = (float*)ws; ws += ND * 4;
  float* e22 = (float*)ws; ws += ND * 4;
  float* e32 = (float*)ws; ws += ND * 4;
  uint2* binned = (uint2*)ws; ws += (size_t)NBUCK * CAP * 8;  // 28.8 MB
  uint32_t* gcursor = (uint32_t*)ws; ws += (size_t)((NBUCK + 63) & ~63) * 4;
  uint32_t* bitmap = (uint32_t*)ws; ws += (size_t)BM_WORDS * 4;

  const int* item_dst = h_item_idx;
  const int* item_src = h_item_idx + NNZ;
  const int* user_dst = h_user_idx;
  const int* user_src = h_user_idx + NNZ;

  const int BIN_BLOCKS = (NNZ + 8191) / 8192;  // 391

  // bitmap of rows actually needed by the output gather
  hipMemsetAsync(bitmap, 0, (size_t)BM_WORDS * 4, stream);
  mark_kernel<<<(BB * LL + 255) / 256, 256, 0, stream>>>(input, bitmap);

  // gate
  gate_kernel<<<2048, 256, 0, stream>>>(user_emb, w0, w1, b0, b1, e20, e30);

  // ---- item graph: bin once, spmm layer1 (full) + layer2 (edge-filtered)
  init_cursor_kernel<<<(NBUCK + 255) / 256, 256, 0, stream>>>(gcursor);
  bin_kernel<<<BIN_BLOCKS, 1024, 0, stream>>>(item_dst, item_src, h_item_val, gcursor, binned);
  bucket_spmm_kernel<false><<<NBUCK, 512, 0, stream>>>(gcursor, binned, e20, e21, nullptr);
  bucket_spmm_kernel<true><<<NBUCK, 512, 0, stream>>>(gcursor, binned, e21, e22, bitmap);

  // ---- user graph
  init_cursor_kernel<<<(NBUCK + 255) / 256, 256, 0, stream>>>(gcursor);
  bin_kernel<<<BIN_BLOCKS, 1024, 0, stream>>>(user_dst, user_src, h_user_val, gcursor, binned);
  bucket_spmm_kernel<false><<<NBUCK, 512, 0, stream>>>(gcursor, binned, e30, e31, nullptr);
  bucket_spmm_kernel<true><<<NBUCK, 512, 0, stream>>>(gcursor, binned, e31, e32, bitmap);

  // ---- fused acc / l2norm / attention-mix / sequence attention
  final_kernel<<<BB, 256, 0, stream>>>(input, e20, e21, e22, e30, e31, e32,
                                       att, att_m, out_Lcas, out_cas);
}

// Round 7
// 668.414 us; speedup vs baseline: 8.7407x; 8.7407x over previous
//
#include <hip/hip_runtime.h>
#include <cstdint>
#include <cstddef>

#define N_NODES 100000
#define D 64
#define NNZ 3200000
#define BB 64
#define LL 200
#define BSHIFT 7
#define BSIZE 128               // nodes per bucket
#define NBUCK 782               // ceil(100000/128)
#define CAP 4608                // max edges per bucket (avg 4092, +8 sigma)
#define EPT 9                   // CAP / 512 threads
#define BM_WORDS 3200           // >= ceil(100000/32)

// ---------------------------------------------------------------- utilities
__device__ __forceinline__ float wave_sum(float x) {
#pragma unroll
  for (int o = 32; o; o >>= 1) x += __shfl_xor(x, o, 64);
  return x;
}

// ---------------------------------------------------------------- mark rows needed by output + compact list
__global__ void mark_kernel(const int* __restrict__ input, uint32_t* __restrict__ bm,
                            int* __restrict__ list, int* __restrict__ nlist) {
  int t = blockIdx.x * 256 + threadIdx.x;
  if (t < BB * LL) {
    int i = input[t];
    uint32_t bit = 1u << (i & 31);
    uint32_t old = atomicOr(&bm[i >> 5], bit);
    if (!(old & bit)) {
      int p = atomicAdd(nlist, 1);
      list[p] = i;
    }
  }
}

// ---------------------------------------------------------------- gate: e2 = u*sigmoid(u@w0+b0), e3 likewise
__global__ __launch_bounds__(256) void gate_kernel(
    const float* __restrict__ u, const float* __restrict__ w0,
    const float* __restrict__ w1, const float* __restrict__ b0,
    const float* __restrict__ b1, float* __restrict__ e2, float* __restrict__ e3) {
  __shared__ float sw0[D * D];
  __shared__ float sw1[D * D];
  __shared__ float sb0[D], sb1[D];
  for (int t = threadIdx.x; t < D * D; t += 256) { sw0[t] = w0[t]; sw1[t] = w1[t]; }
  if (threadIdx.x < D) { sb0[threadIdx.x] = b0[threadIdx.x]; sb1[threadIdx.x] = b1[threadIdx.x]; }
  __syncthreads();
  int wave = (blockIdx.x * 256 + threadIdx.x) >> 6;
  int lane = threadIdx.x & 63;
  int nw = (gridDim.x * 256) >> 6;
  for (int i = wave; i < N_NODES; i += nw) {
    float uv = u[i * D + lane];
    float a0 = 0.f, a1 = 0.f;
#pragma unroll
    for (int k = 0; k < D; ++k) {
      float uk = __shfl(uv, k, 64);
      a0 = fmaf(uk, sw0[k * D + lane], a0);
      a1 = fmaf(uk, sw1[k * D + lane], a1);
    }
    a0 += sb0[lane];
    a1 += sb1[lane];
    float s0 = 1.f / (1.f + expf(-a0));
    float s1 = 1.f / (1.f + expf(-a1));
    e2[i * D + lane] = uv * s0;
    e3[i * D + lane] = uv * s1;
  }
}

// ---------------------------------------------------------------- bucket binning
__global__ void init_cursor_kernel(uint32_t* __restrict__ gcursor) {
  int t = blockIdx.x * 256 + threadIdx.x;
  if (t < NBUCK) gcursor[t] = (uint32_t)t * CAP;
}

// chunk of 8192 edges per block; per-block LDS histogram -> one global atomic
// per present bucket -> direct positioned writes (bursts within buckets).
__global__ __launch_bounds__(1024) void bin_kernel(
    const int* __restrict__ dsts, const int* __restrict__ srcs,
    const float* __restrict__ val, uint32_t* __restrict__ gcursor,
    uint2* __restrict__ binned) {
  __shared__ uint32_t hist[NBUCK];
  __shared__ uint32_t gbase[NBUCK];
  const int CHUNK = 8192;
  int base = blockIdx.x * CHUNK;
  int tid = threadIdx.x;
  for (int t = tid; t < NBUCK; t += 1024) hist[t] = 0u;
  __syncthreads();
  int n = NNZ - base;
  if (n > CHUNK) n = CHUNK;
  uint32_t px[8]; float pv[8]; uint32_t pb[8]; uint32_t pr[8];
#pragma unroll
  for (int k = 0; k < 8; ++k) {
    int off = (k << 10) + tid;
    bool ok = off < n;
    int e = base + off;
    int d = ok ? dsts[e] : 0;
    int s = ok ? srcs[e] : 0;
    float v = ok ? val[e] : 0.f;
    uint32_t b = (uint32_t)d >> BSHIFT;
    pb[k] = ok ? b : 0xFFFFFFFFu;
    pr[k] = ok ? atomicAdd(&hist[b], 1u) : 0u;
    px[k] = (uint32_t)s | ((uint32_t)(d & (BSIZE - 1)) << 17);
    pv[k] = v;
  }
  __syncthreads();
  for (int t = tid; t < NBUCK; t += 1024) {
    uint32_t h = hist[t];
    gbase[t] = h ? atomicAdd(&gcursor[t], h) : 0u;
  }
  __syncthreads();
#pragma unroll
  for (int k = 0; k < 8; ++k) {
    if (pb[k] != 0xFFFFFFFFu) {
      uint32_t pos = gbase[pb[k]] + pr[k];
      uint32_t lim = (pb[k] + 1u) * CAP;
      if (pos < lim) {  // overflow guard: never corrupt the next bucket
        binned[pos] = make_uint2(px[k], __float_as_uint(pv[k]));
      }
    }
  }
}

// ---------------------------------------------------------------- sort + spmm (layer 1)
// One block per bucket. In-LDS counting sort of ~4096 edges by local row (128 rows),
// then wave-per-row quad-ILP float4 gather with REGISTER accumulation (no atomics).
// Also writes sorted pairs back to `binned` + per-node (start,cnt) for layer 2.
__global__ __launch_bounds__(512) void sortspmm_kernel(
    const uint32_t* __restrict__ gcursor, uint2* __restrict__ binned,
    const float* __restrict__ xin, float* __restrict__ xout,
    uint32_t* __restrict__ grow_start, uint32_t* __restrict__ grow_cnt) {
  __shared__ uint2 sp[CAP];           // 36864 B sorted pairs
  __shared__ uint32_t hist[BSIZE];    // per-row counts
  __shared__ uint32_t ssc[BSIZE];     // scan buffer
  __shared__ uint32_t sst[BSIZE];     // exclusive row starts
  int bucket = blockIdx.x, tid = threadIdx.x;
  int nodebase = bucket << BSHIFT;
  uint32_t cnt = gcursor[bucket] - (uint32_t)bucket * CAP;
  if (cnt > CAP) cnt = CAP;
  if (tid < BSIZE) hist[tid] = 0u;
  __syncthreads();
  // load edges to registers + rank within row via LDS atomic (128 counters, low contention)
  uint2 pr[EPT]; uint32_t rk[EPT];
  const uint2* ep = binned + (size_t)bucket * CAP;
#pragma unroll
  for (int k = 0; k < EPT; ++k) {
    int e = (k << 9) + tid;
    if (e < (int)cnt) {
      pr[k] = ep[e];
      rk[k] = atomicAdd(&hist[pr[k].x >> 17], 1u);
    }
  }
  __syncthreads();
  // inclusive scan of 128 counts (Hillis-Steele, uniform barriers)
  if (tid < BSIZE) ssc[tid] = hist[tid];
  __syncthreads();
  for (int o = 1; o < BSIZE; o <<= 1) {
    uint32_t t = 0;
    if (tid < BSIZE && tid >= o) t = ssc[tid - o];
    __syncthreads();
    if (tid < BSIZE) ssc[tid] += t;
    __syncthreads();
  }
  if (tid < BSIZE) sst[tid] = ssc[tid] - hist[tid];
  __syncthreads();
  // scatter into row-sorted LDS array
#pragma unroll
  for (int k = 0; k < EPT; ++k) {
    int e = (k << 9) + tid;
    if (e < (int)cnt) sp[sst[pr[k].x >> 17] + rk[k]] = pr[k];
  }
  __syncthreads();
  // write back sorted pairs + row meta (consumed by the layer-2 list pass)
  for (int t = tid; t < (int)cnt; t += 512) binned[(size_t)bucket * CAP + t] = sp[t];
  int nvalid = N_NODES - nodebase;
  if (nvalid > BSIZE) nvalid = BSIZE;
  if (tid < nvalid) {
    grow_start[nodebase + tid] = (uint32_t)bucket * CAP + sst[tid];
    grow_cnt[nodebase + tid] = hist[tid];
  }
  // wave-per-row spmm: lane = g*16+c, group g handles edges j+g, c owns cols 4c..4c+3
  int wave = tid >> 6, lane = tid & 63, g = lane >> 4, c = lane & 15;
  for (int r = wave; r < nvalid; r += 8) {
    uint32_t rc = hist[r], s0 = sst[r];
    float ax = 0.f, ay = 0.f, az = 0.f, aw = 0.f;
    uint32_t rc4 = (rc + 3u) & ~3u;
    for (uint32_t j = 0; j < rc4; j += 4) {
      uint32_t e = j + (uint32_t)g;
      uint2 p = make_uint2(0u, 0u);
      if (e < rc) p = sp[s0 + e];           // 16-lane LDS broadcast, 4 addrs/wave
      float v = __uint_as_float(p.y);
      uint32_t src = p.x & 0x1FFFFu;        // masked tail: src=0, v=0 (row 0 L1-hot)
      float4 xv = ((const float4*)(xin + (size_t)src * D))[c];
      ax = fmaf(v, xv.x, ax); ay = fmaf(v, xv.y, ay);
      az = fmaf(v, xv.z, az); aw = fmaf(v, xv.w, aw);
    }
#pragma unroll
    for (int o = 16; o <= 32; o <<= 1) {
      ax += __shfl_xor(ax, o, 64); ay += __shfl_xor(ay, o, 64);
      az += __shfl_xor(az, o, 64); aw += __shfl_xor(aw, o, 64);
    }
    if (g == 0)
      ((float4*)(xout + (size_t)(nodebase + r) * D))[c] = make_float4(ax, ay, az, aw);
  }
}

// ---------------------------------------------------------------- layer-2 spmm over marked rows only
__global__ __launch_bounds__(256) void listspmm_kernel(
    const uint32_t* __restrict__ grow_start, const uint32_t* __restrict__ grow_cnt,
    const uint2* __restrict__ pairs, const float* __restrict__ xin,
    float* __restrict__ xout, const int* __restrict__ list, const int* __restrict__ nlist) {
  int wave = (blockIdx.x * 256 + threadIdx.x) >> 6;
  int lane = threadIdx.x & 63;
  int nw = (gridDim.x * 256) >> 6;
  int g = lane >> 4, c = lane & 15;
  int n = nlist[0];
  for (int ii = wave; ii < n; ii += nw) {
    int i = list[ii];
    uint32_t rc = grow_cnt[i];
    uint32_t base = grow_start[i];
    float ax = 0.f, ay = 0.f, az = 0.f, aw = 0.f;
    uint32_t rc4 = (rc + 3u) & ~3u;
    for (uint32_t j = 0; j < rc4; j += 4) {
      uint32_t e = j + (uint32_t)g;
      uint2 p = make_uint2(0u, 0u);
      if (e < rc) p = pairs[base + e];
      float v = __uint_as_float(p.y);
      uint32_t src = p.x & 0x1FFFFu;
      float4 xv = ((const float4*)(xin + (size_t)src * D))[c];
      ax = fmaf(v, xv.x, ax); ay = fmaf(v, xv.y, ay);
      az = fmaf(v, xv.z, az); aw = fmaf(v, xv.w, aw);
    }
#pragma unroll
    for (int o = 16; o <= 32; o <<= 1) {
      ax += __shfl_xor(ax, o, 64); ay += __shfl_xor(ay, o, 64);
      az += __shfl_xor(az, o, 64); aw += __shfl_xor(aw, o, 64);
    }
    if (g == 0)
      ((float4*)(xout + (size_t)i * D))[c] = make_float4(ax, ay, az, aw);
  }
}

// ---------------------------------------------------------------- final: fused acc/l2norm/mix + seq attention
__global__ __launch_bounds__(256) void final_kernel(
    const int* __restrict__ input,
    const float* __restrict__ e20, const float* __restrict__ e21, const float* __restrict__ e22,
    const float* __restrict__ e30, const float* __restrict__ e31, const float* __restrict__ e32,
    const float* __restrict__ att, const float* __restrict__ att_m,
    float* __restrict__ out_Lcas, float* __restrict__ out_cas) {
  __shared__ float cas[LL * D];  // 51.2 KB
  __shared__ float sv[D];
  __shared__ float sscore[LL];
  __shared__ float red[8];
  int b = blockIdx.x, tid = threadIdx.x;
  if (tid < D) {
    float a = 0.f;
#pragma unroll
    for (int j = 0; j < D; ++j) a = fmaf(att_m[tid * D + j], att[j], a);
    sv[tid] = a;
  }
  __syncthreads();
  int wv = tid >> 6, lane = tid & 63;
  float svl = sv[lane];
  for (int l = wv; l < LL; l += 4) {
    int i = input[b * LL + l];
    size_t o = (size_t)i * D + lane;
    float v20 = e20[o], v21 = e21[o], v22 = e22[o];
    float v30 = e30[o], v31 = e31[o], v32 = e32[o];
    float n21 = fmaxf(sqrtf(wave_sum(v21 * v21)), 1e-12f);
    float n22 = fmaxf(sqrtf(wave_sum(v22 * v22)), 1e-12f);
    float n31 = fmaxf(sqrtf(wave_sum(v31 * v31)), 1e-12f);
    float n32 = fmaxf(sqrtf(wave_sum(v32 * v32)), 1e-12f);
    float a2 = v20 + v21 / n21 + v22 / n22;
    float a3 = v30 + v31 / n31 + v32 / n32;
    float w2 = wave_sum(a2 * svl);
    float w3 = wave_sum(a3 * svl);
    float mx = fmaxf(w2, w3);
    float ex2 = expf(w2 - mx), ex3 = expf(w3 - mx);
    float inv = 1.f / (ex2 + ex3);
    float mix = (ex2 * a2 + ex3 * a3) * inv;
    cas[l * D + lane] = mix;
    out_cas[(size_t)(b * LL + l) * D + lane] = mix;
  }
  __syncthreads();
  for (int l = wv; l < LL; l += 4) {
    float s = wave_sum(cas[lane] * cas[l * D + lane]) * 0.125f;  // 1/sqrt(64)
    int iv = input[b * LL + l];
    s = (iv == 0) ? -1e9f : s;
    if (lane == 0) sscore[l] = s;
  }
  __syncthreads();
  float m = -INFINITY;
  for (int l = tid; l < LL; l += 256) m = fmaxf(m, sscore[l]);
#pragma unroll
  for (int o = 32; o; o >>= 1) m = fmaxf(m, __shfl_xor(m, o, 64));
  if (lane == 0) red[wv] = m;
  __syncthreads();
  m = fmaxf(fmaxf(red[0], red[1]), fmaxf(red[2], red[3]));
  float sum = 0.f;
  for (int l = tid; l < LL; l += 256) sum += expf(sscore[l] - m);
  sum = wave_sum(sum);
  if (lane == 0) red[4 + wv] = sum;
  __syncthreads();
  float inv = 1.f / (red[4] + red[5] + red[6] + red[7]);
  for (int l = tid; l < LL; l += 256) sscore[l] = expf(sscore[l] - m) * inv;
  __syncthreads();
  for (int t = tid; t < LL * D; t += 256)
    out_Lcas[(size_t)b * LL * D + t] = sscore[t >> 6] * cas[t];
}

// ---------------------------------------------------------------- launch
extern "C" void kernel_launch(void* const* d_in, const int* in_sizes, int n_in,
                              void* d_out, int out_size, void* d_ws, size_t ws_size,
                              hipStream_t stream) {
  const int* input = (const int*)d_in[0];
  const int* h_item_idx = (const int*)d_in[1];
  const float* h_item_val = (const float*)d_in[2];
  const int* h_user_idx = (const int*)d_in[3];
  const float* h_user_val = (const float*)d_in[4];
  const float* user_emb = (const float*)d_in[5];
  const float* w0 = (const float*)d_in[6];
  const float* w1 = (const float*)d_in[7];
  const float* b0 = (const float*)d_in[8];
  const float* b1 = (const float*)d_in[9];
  const float* att = (const float*)d_in[10];
  const float* att_m = (const float*)d_in[11];

  float* out = (float*)d_out;
  float* out_Lcas = out;                       // B*L*D
  float* out_cas = out + (size_t)BB * LL * D;  // B*L*D

  const size_t ND = (size_t)N_NODES * D;  // 6.4M floats
  char* ws = (char*)d_ws;
  float* e20 = (float*)ws; ws += ND * 4;
  float* e30 = (float*)ws; ws += ND * 4;
  float* e21 = (float*)ws; ws += ND * 4;
  float* e31 = (float*)ws; ws += ND * 4;
  float* e22 = (float*)ws; ws += ND * 4;
  float* e32 = (float*)ws; ws += ND * 4;
  uint2* binned = (uint2*)ws; ws += (size_t)NBUCK * CAP * 8;  // 28.8 MB
  uint32_t* gcursor = (uint32_t*)ws; ws += (size_t)((NBUCK + 63) & ~63) * 4;
  uint32_t* bitmap = (uint32_t*)ws; ws += (size_t)BM_WORDS * 4;
  uint32_t* grow_start = (uint32_t*)ws; ws += (size_t)N_NODES * 4;
  uint32_t* grow_cnt = (uint32_t*)ws; ws += (size_t)N_NODES * 4;
  int* list = (int*)ws; ws += (size_t)(BB * LL) * 4;
  int* nlist = (int*)ws; ws += 64;

  const int* item_dst = h_item_idx;
  const int* item_src = h_item_idx + NNZ;
  const int* user_dst = h_user_idx;
  const int* user_src = h_user_idx + NNZ;

  const int BIN_BLOCKS = (NNZ + 8191) / 8192;  // 391

  // bitmap + compact list of rows actually needed by the output gather
  hipMemsetAsync(bitmap, 0, (size_t)BM_WORDS * 4, stream);
  hipMemsetAsync(nlist, 0, 64, stream);
  mark_kernel<<<(BB * LL + 255) / 256, 256, 0, stream>>>(input, bitmap, list, nlist);

  // gate
  gate_kernel<<<2048, 256, 0, stream>>>(user_emb, w0, w1, b0, b1, e20, e30);

  // ---- item graph: bin -> sort+spmm layer1 (full) -> list spmm layer2 (marked rows)
  init_cursor_kernel<<<(NBUCK + 255) / 256, 256, 0, stream>>>(gcursor);
  bin_kernel<<<BIN_BLOCKS, 1024, 0, stream>>>(item_dst, item_src, h_item_val, gcursor, binned);
  sortspmm_kernel<<<NBUCK, 512, 0, stream>>>(gcursor, binned, e20, e21, grow_start, grow_cnt);
  listspmm_kernel<<<3200, 256, 0, stream>>>(grow_start, grow_cnt, binned, e21, e22, list, nlist);

  // ---- user graph
  init_cursor_kernel<<<(NBUCK + 255) / 256, 256, 0, stream>>>(gcursor);
  bin_kernel<<<BIN_BLOCKS, 1024, 0, stream>>>(user_dst, user_src, h_user_val, gcursor, binned);
  sortspmm_kernel<<<NBUCK, 512, 0, stream>>>(gcursor, binned, e30, e31, grow_start, grow_cnt);
  listspmm_kernel<<<3200, 256, 0, stream>>>(grow_start, grow_cnt, binned, e31, e32, list, nlist);

  // ---- fused acc / l2norm / attention-mix / sequence attention
  final_kernel<<<BB, 256, 0, stream>>>(input, e20, e21, e22, e30, e31, e32,
                                       att, att_m, out_Lcas, out_cas);
}

// Round 9
// 662.058 us; speedup vs baseline: 8.8246x; 1.0096x over previous
//
#include <hip/hip_runtime.h>
#include <cstdint>
#include <cstddef>

#define N_NODES 100000
#define D 64
#define NNZ 3200000
#define BB 64
#define LL 200
#define BSHIFT 7
#define BSIZE 128               // nodes per bucket
#define NBUCK 782               // ceil(100000/128)
#define CAP 4608                // max edges per bucket (avg 4092, +8 sigma)
#define EPT 9                   // CAP / 512 threads (sortspmm)
#define BM_WORDS 3200           // >= ceil(100000/32)
#define BCHUNK 4096             // edges per bin block
#define BEPT 4                  // BCHUNK / 1024 threads

// ---------------------------------------------------------------- utilities
__device__ __forceinline__ float wave_sum(float x) {
#pragma unroll
  for (int o = 32; o; o >>= 1) x += __shfl_xor(x, o, 64);
  return x;
}

// ---------------------------------------------------------------- mark rows needed by output + compact list
__global__ void mark_kernel(const int* __restrict__ input, uint32_t* __restrict__ bm,
                            int* __restrict__ list, int* __restrict__ nlist) {
  int t = blockIdx.x * 256 + threadIdx.x;
  if (t < BB * LL) {
    int i = input[t];
    uint32_t bit = 1u << (i & 31);
    uint32_t old = atomicOr(&bm[i >> 5], bit);
    if (!(old & bit)) {
      int p = atomicAdd(nlist, 1);
      list[p] = i;
    }
  }
}

// ---------------------------------------------------------------- gate: e2 = u*sigmoid(u@w0+b0), e3 likewise
__global__ __launch_bounds__(256) void gate_kernel(
    const float* __restrict__ u, const float* __restrict__ w0,
    const float* __restrict__ w1, const float* __restrict__ b0,
    const float* __restrict__ b1, float* __restrict__ e2, float* __restrict__ e3) {
  __shared__ float sw0[D * D];
  __shared__ float sw1[D * D];
  __shared__ float sb0[D], sb1[D];
  for (int t = threadIdx.x; t < D * D; t += 256) { sw0[t] = w0[t]; sw1[t] = w1[t]; }
  if (threadIdx.x < D) { sb0[threadIdx.x] = b0[threadIdx.x]; sb1[threadIdx.x] = b1[threadIdx.x]; }
  __syncthreads();
  int wave = (blockIdx.x * 256 + threadIdx.x) >> 6;
  int lane = threadIdx.x & 63;
  int nw = (gridDim.x * 256) >> 6;
  for (int i = wave; i < N_NODES; i += nw) {
    float uv = u[i * D + lane];
    float a0 = 0.f, a1 = 0.f;
#pragma unroll
    for (int k = 0; k < D; ++k) {
      float uk = __shfl(uv, k, 64);
      a0 = fmaf(uk, sw0[k * D + lane], a0);
      a1 = fmaf(uk, sw1[k * D + lane], a1);
    }
    a0 += sb0[lane];
    a1 += sb1[lane];
    float s0 = 1.f / (1.f + expf(-a0));
    float s1 = 1.f / (1.f + expf(-a1));
    e2[i * D + lane] = uv * s0;
    e3[i * D + lane] = uv * s1;
  }
}

// ---------------------------------------------------------------- bucket binning
__global__ void init_cursor_kernel(uint32_t* __restrict__ gcursor) {
  int t = blockIdx.x * 256 + threadIdx.x;
  if (t < NBUCK) gcursor[t] = (uint32_t)t * CAP;
}

// chunk of 4096 edges per block; LDS counting-sort by bucket, then COALESCED
// write-out (consecutive tid -> consecutive global addr within bucket runs).
__global__ __launch_bounds__(1024) void bin_kernel(
    const int* __restrict__ dsts, const int* __restrict__ srcs,
    const float* __restrict__ val, uint32_t* __restrict__ gcursor,
    uint2* __restrict__ binned) {
  __shared__ uint2 sp[BCHUNK];          // 32 KB bucket-sorted pairs
  __shared__ uint32_t hist[NBUCK];      // per-bucket counts (then preserved)
  __shared__ uint32_t sst[NBUCK + 1];   // exclusive bucket starts (scan)
  __shared__ uint32_t gbase[NBUCK];     // global base per bucket
  int base = blockIdx.x * BCHUNK;
  int tid = threadIdx.x;
  for (int t = tid; t < NBUCK; t += 1024) hist[t] = 0u;
  __syncthreads();
  int n = NNZ - base;
  if (n > BCHUNK) n = BCHUNK;
  uint32_t px[BEPT]; float pv[BEPT]; uint32_t pb[BEPT]; uint32_t pr[BEPT];
#pragma unroll
  for (int k = 0; k < BEPT; ++k) {
    int off = (k << 10) + tid;
    bool ok = off < n;
    int e = base + off;
    int d = ok ? dsts[e] : 0;
    int s = ok ? srcs[e] : 0;
    float v = ok ? val[e] : 0.f;
    uint32_t b = (uint32_t)d >> BSHIFT;
    pb[k] = ok ? b : 0xFFFFFFFFu;
    pr[k] = ok ? atomicAdd(&hist[b], 1u) : 0u;
    px[k] = (uint32_t)s | ((uint32_t)(d & (BSIZE - 1)) << 17);
    pv[k] = v;
  }
  __syncthreads();
  // gbase atomics (independent of scan) + seed scan array: sst[i+1] = hist[i]
  for (int t = tid; t < NBUCK; t += 1024) {
    uint32_t h = hist[t];
    gbase[t] = h ? atomicAdd(&gcursor[t], h) : 0u;
    sst[t + 1] = h;
  }
  if (tid == 0) sst[0] = 0u;
  __syncthreads();
  // inclusive scan over sst[1..NBUCK] (Hillis-Steele; element i = tid+1)
  for (int o = 1; o < NBUCK; o <<= 1) {
    uint32_t t = 0u;
    if (tid < NBUCK && (int)(tid + 1) > o) t = sst[tid + 1 - o];
    __syncthreads();
    if (tid < NBUCK && (int)(tid + 1) > o) sst[tid + 1] += t;
    __syncthreads();
  }
  // scatter into bucket-sorted LDS
#pragma unroll
  for (int k = 0; k < BEPT; ++k) {
    if (pb[k] != 0xFFFFFFFFu)
      sp[sst[pb[k]] + pr[k]] = make_uint2(px[k], __float_as_uint(pv[k]));
  }
  __syncthreads();
  // coalesced write-out: find bucket of idx by binary search over sst
  for (int idx = tid; idx < n; idx += 1024) {
    int lo = 0, hi = NBUCK;  // invariant: sst[lo] <= idx < sst[hi]
    while (hi - lo > 1) {
      int mid = (lo + hi) >> 1;
      if ((int)sst[mid] <= idx) lo = mid; else hi = mid;
    }
    uint32_t pos = gbase[lo] + ((uint32_t)idx - sst[lo]);
    if (pos < (uint32_t)(lo + 1) * CAP) {  // overflow guard
      binned[pos] = sp[idx];
    }
  }
}

// ---------------------------------------------------------------- sort + spmm (layer 1)
// One block per bucket. In-LDS counting sort of ~4096 edges by local row (128 rows),
// then wave-per-row 8-edge-unrolled float4 gather with REGISTER accumulation.
// Also writes sorted pairs back to `binned` + per-node (start,cnt) for layer 2.
__global__ __launch_bounds__(512) void sortspmm_kernel(
    const uint32_t* __restrict__ gcursor, uint2* __restrict__ binned,
    const float* __restrict__ xin, float* __restrict__ xout,
    uint32_t* __restrict__ grow_start, uint32_t* __restrict__ grow_cnt) {
  __shared__ uint2 sp[CAP];           // 36864 B sorted pairs
  __shared__ uint32_t hist[BSIZE];    // per-row counts
  __shared__ uint32_t ssc[BSIZE];     // scan buffer
  __shared__ uint32_t sst[BSIZE];     // exclusive row starts
  int bucket = blockIdx.x, tid = threadIdx.x;
  int nodebase = bucket << BSHIFT;
  uint32_t cnt = gcursor[bucket] - (uint32_t)bucket * CAP;
  if (cnt > CAP) cnt = CAP;
  if (tid < BSIZE) hist[tid] = 0u;
  __syncthreads();
  // load edges to registers + rank within row via LDS atomic (128 counters)
  uint2 pr[EPT]; uint32_t rk[EPT];
  const uint2* ep = binned + (size_t)bucket * CAP;
#pragma unroll
  for (int k = 0; k < EPT; ++k) {
    int e = (k << 9) + tid;
    if (e < (int)cnt) {
      pr[k] = ep[e];
      rk[k] = atomicAdd(&hist[pr[k].x >> 17], 1u);
    }
  }
  __syncthreads();
  // inclusive scan of 128 counts (Hillis-Steele, uniform barriers)
  if (tid < BSIZE) ssc[tid] = hist[tid];
  __syncthreads();
  for (int o = 1; o < BSIZE; o <<= 1) {
    uint32_t t = 0;
    if (tid < BSIZE && tid >= o) t = ssc[tid - o];
    __syncthreads();
    if (tid < BSIZE) ssc[tid] += t;
    __syncthreads();
  }
  if (tid < BSIZE) sst[tid] = ssc[tid] - hist[tid];
  __syncthreads();
  // scatter into row-sorted LDS array
#pragma unroll
  for (int k = 0; k < EPT; ++k) {
    int e = (k << 9) + tid;
    if (e < (int)cnt) sp[sst[pr[k].x >> 17] + rk[k]] = pr[k];
  }
  __syncthreads();
  // write back sorted pairs + row meta (consumed by the layer-2 list pass)
  for (int t = tid; t < (int)cnt; t += 512) binned[(size_t)bucket * CAP + t] = sp[t];
  int nvalid = N_NODES - nodebase;
  if (nvalid > BSIZE) nvalid = BSIZE;
  if (tid < nvalid) {
    grow_start[nodebase + tid] = (uint32_t)bucket * CAP + sst[tid];
    grow_cnt[nodebase + tid] = hist[tid];
  }
  // wave-per-row spmm: lane = g*16+c; 8 edges per iter (2 independent gathers)
  int wave = tid >> 6, lane = tid & 63, g = lane >> 4, c = lane & 15;
  for (int r = wave; r < nvalid; r += 8) {
    uint32_t rc = hist[r], s0 = sst[r];
    float ax = 0.f, ay = 0.f, az = 0.f, aw = 0.f;
    uint32_t rc8 = (rc + 7u) & ~7u;
    for (uint32_t j = 0; j < rc8; j += 8) {
      uint32_t e0 = j + (uint32_t)g;
      uint32_t e1 = e0 + 4u;
      uint2 p0 = make_uint2(0u, 0u), p1 = make_uint2(0u, 0u);
      if (e0 < rc) p0 = sp[s0 + e0];
      if (e1 < rc) p1 = sp[s0 + e1];
      float v0 = __uint_as_float(p0.y), v1 = __uint_as_float(p1.y);
      uint32_t sA = p0.x & 0x1FFFFu, sB = p1.x & 0x1FFFFu;
      float4 x0 = ((const float4*)(xin + (size_t)sA * D))[c];
      float4 x1 = ((const float4*)(xin + (size_t)sB * D))[c];
      ax = fmaf(v0, x0.x, ax); ay = fmaf(v0, x0.y, ay);
      az = fmaf(v0, x0.z, az); aw = fmaf(v0, x0.w, aw);
      ax = fmaf(v1, x1.x, ax); ay = fmaf(v1, x1.y, ay);
      az = fmaf(v1, x1.z, az); aw = fmaf(v1, x1.w, aw);
    }
#pragma unroll
    for (int o = 16; o <= 32; o <<= 1) {
      ax += __shfl_xor(ax, o, 64); ay += __shfl_xor(ay, o, 64);
      az += __shfl_xor(az, o, 64); aw += __shfl_xor(aw, o, 64);
    }
    if (g == 0)
      ((float4*)(xout + (size_t)(nodebase + r) * D))[c] = make_float4(ax, ay, az, aw);
  }
}

// ---------------------------------------------------------------- layer-2 spmm over marked rows only
__global__ __launch_bounds__(256) void listspmm_kernel(
    const uint32_t* __restrict__ grow_start, const uint32_t* __restrict__ grow_cnt,
    const uint2* __restrict__ pairs, const float* __restrict__ xin,
    float* __restrict__ xout, const int* __restrict__ list, const int* __restrict__ nlist) {
  int wave = (blockIdx.x * 256 + threadIdx.x) >> 6;
  int lane = threadIdx.x & 63;
  int nw = (gridDim.x * 256) >> 6;
  int g = lane >> 4, c = lane & 15;
  int n = nlist[0];
  for (int ii = wave; ii < n; ii += nw) {
    int i = list[ii];
    uint32_t rc = grow_cnt[i];
    uint32_t base = grow_start[i];
    float ax = 0.f, ay = 0.f, az = 0.f, aw = 0.f;
    uint32_t rc8 = (rc + 7u) & ~7u;
    for (uint32_t j = 0; j < rc8; j += 8) {
      uint32_t e0 = j + (uint32_t)g;
      uint32_t e1 = e0 + 4u;
      uint2 p0 = make_uint2(0u, 0u), p1 = make_uint2(0u, 0u);
      if (e0 < rc) p0 = pairs[base + e0];
      if (e1 < rc) p1 = pairs[base + e1];
      float v0 = __uint_as_float(p0.y), v1 = __uint_as_float(p1.y);
      uint32_t sA = p0.x & 0x1FFFFu, sB = p1.x & 0x1FFFFu;
      float4 x0 = ((const float4*)(xin + (size_t)sA * D))[c];
      float4 x1 = ((const float4*)(xin + (size_t)sB * D))[c];
      ax = fmaf(v0, x0.x, ax); ay = fmaf(v0, x0.y, ay);
      az = fmaf(v0, x0.z, az); aw = fmaf(v0, x0.w, aw);
      ax = fmaf(v1, x1.x, ax); ay = fmaf(v1, x1.y, ay);
      az = fmaf(v1, x1.z, az); aw = fmaf(v1, x1.w, aw);
    }
#pragma unroll
    for (int o = 16; o <= 32; o <<= 1) {
      ax += __shfl_xor(ax, o, 64); ay += __shfl_xor(ay, o, 64);
      az += __shfl_xor(az, o, 64); aw += __shfl_xor(aw, o, 64);
    }
    if (g == 0)
      ((float4*)(xout + (size_t)i * D))[c] = make_float4(ax, ay, az, aw);
  }
}

// ---------------------------------------------------------------- final: fused acc/l2norm/mix + seq attention
__global__ __launch_bounds__(256) void final_kernel(
    const int* __restrict__ input,
    const float* __restrict__ e20, const float* __restrict__ e21, const float* __restrict__ e22,
    const float* __restrict__ e30, const float* __restrict__ e31, const float* __restrict__ e32,
    const float* __restrict__ att, const float* __restrict__ att_m,
    float* __restrict__ out_Lcas, float* __restrict__ out_cas) {
  __shared__ float cas[LL * D];  // 51.2 KB
  __shared__ float sv[D];
  __shared__ float sscore[LL];
  __shared__ float red[8];
  int b = blockIdx.x, tid = threadIdx.x;
  if (tid < D) {
    float a = 0.f;
#pragma unroll
    for (int j = 0; j < D; ++j) a = fmaf(att_m[tid * D + j], att[j], a);
    sv[tid] = a;
  }
  __syncthreads();
  int wv = tid >> 6, lane = tid & 63;
  float svl = sv[lane];
  for (int l = wv; l < LL; l += 4) {
    int i = input[b * LL + l];
    size_t o = (size_t)i * D + lane;
    float v20 = e20[o], v21 = e21[o], v22 = e22[o];
    float v30 = e30[o], v31 = e31[o], v32 = e32[o];
    float n21 = fmaxf(sqrtf(wave_sum(v21 * v21)), 1e-12f);
    float n22 = fmaxf(sqrtf(wave_sum(v22 * v22)), 1e-12f);
    float n31 = fmaxf(sqrtf(wave_sum(v31 * v31)), 1e-12f);
    float n32 = fmaxf(sqrtf(wave_sum(v32 * v32)), 1e-12f);
    float a2 = v20 + v21 / n21 + v22 / n22;
    float a3 = v30 + v31 / n31 + v32 / n32;
    float w2 = wave_sum(a2 * svl);
    float w3 = wave_sum(a3 * svl);
    float mx = fmaxf(w2, w3);
    float ex2 = expf(w2 - mx), ex3 = expf(w3 - mx);
    float inv = 1.f / (ex2 + ex3);
    float mix = (ex2 * a2 + ex3 * a3) * inv;
    cas[l * D + lane] = mix;
    out_cas[(size_t)(b * LL + l) * D + lane] = mix;
  }
  __syncthreads();
  for (int l = wv; l < LL; l += 4) {
    float s = wave_sum(cas[lane] * cas[l * D + lane]) * 0.125f;  // 1/sqrt(64)
    int iv = input[b * LL + l];
    s = (iv == 0) ? -1e9f : s;
    if (lane == 0) sscore[l] = s;
  }
  __syncthreads();
  float m = -INFINITY;
  for (int l = tid; l < LL; l += 256) m = fmaxf(m, sscore[l]);
#pragma unroll
  for (int o = 32; o; o >>= 1) m = fmaxf(m, __shfl_xor(m, o, 64));
  if (lane == 0) red[wv] = m;
  __syncthreads();
  m = fmaxf(fmaxf(red[0], red[1]), fmaxf(red[2], red[3]));
  float sum = 0.f;
  for (int l = tid; l < LL; l += 256) sum += expf(sscore[l] - m);
  sum = wave_sum(sum);
  if (lane == 0) red[4 + wv] = sum;
  __syncthreads();
  float inv = 1.f / (red[4] + red[5] + red[6] + red[7]);
  for (int l = tid; l < LL; l += 256) sscore[l] = expf(sscore[l] - m) * inv;
  __syncthreads();
  for (int t = tid; t < LL * D; t += 256)
    out_Lcas[(size_t)b * LL * D + t] = sscore[t >> 6] * cas[t];
}

// ---------------------------------------------------------------- launch
extern "C" void kernel_launch(void* const* d_in, const int* in_sizes, int n_in,
                              void* d_out, int out_size, void* d_ws, size_t ws_size,
                              hipStream_t stream) {
  const int* input = (const int*)d_in[0];
  const int* h_item_idx = (const int*)d_in[1];
  const float* h_item_val = (const float*)d_in[2];
  const int* h_user_idx = (const int*)d_in[3];
  const float* h_user_val = (const float*)d_in[4];
  const float* user_emb = (const float*)d_in[5];
  const float* w0 = (const float*)d_in[6];
  const float* w1 = (const float*)d_in[7];
  const float* b0 = (const float*)d_in[8];
  const float* b1 = (const float*)d_in[9];
  const float* att = (const float*)d_in[10];
  const float* att_m = (const float*)d_in[11];

  float* out = (float*)d_out;
  float* out_Lcas = out;                       // B*L*D
  float* out_cas = out + (size_t)BB * LL * D;  // B*L*D

  const size_t ND = (size_t)N_NODES * D;  // 6.4M floats
  char* ws = (char*)d_ws;
  float* e20 = (float*)ws; ws += ND * 4;
  float* e30 = (float*)ws; ws += ND * 4;
  float* e21 = (float*)ws; ws += ND * 4;
  float* e31 = (float*)ws; ws += ND * 4;
  float* e22 = (float*)ws; ws += ND * 4;
  float* e32 = (float*)ws; ws += ND * 4;
  uint2* binned = (uint2*)ws; ws += (size_t)NBUCK * CAP * 8;  // 28.8 MB
  uint32_t* gcursor = (uint32_t*)ws; ws += (size_t)((NBUCK + 63) & ~63) * 4;
  uint32_t* bitmap = (uint32_t*)ws; ws += (size_t)BM_WORDS * 4;
  uint32_t* grow_start = (uint32_t*)ws; ws += (size_t)N_NODES * 4;
  uint32_t* grow_cnt = (uint32_t*)ws; ws += (size_t)N_NODES * 4;
  int* list = (int*)ws; ws += (size_t)(BB * LL) * 4;
  int* nlist = (int*)ws; ws += 64;

  const int* item_dst = h_item_idx;
  const int* item_src = h_item_idx + NNZ;
  const int* user_dst = h_user_idx;
  const int* user_src = h_user_idx + NNZ;

  const int BIN_BLOCKS = (NNZ + BCHUNK - 1) / BCHUNK;  // 782

  // bitmap + compact list of rows actually needed by the output gather
  hipMemsetAsync(bitmap, 0, (size_t)BM_WORDS * 4, stream);
  hipMemsetAsync(nlist, 0, 64, stream);
  mark_kernel<<<(BB * LL + 255) / 256, 256, 0, stream>>>(input, bitmap, list, nlist);

  // gate
  gate_kernel<<<2048, 256, 0, stream>>>(user_emb, w0, w1, b0, b1, e20, e30);

  // ---- item graph: bin -> sort+spmm layer1 (full) -> list spmm layer2 (marked rows)
  init_cursor_kernel<<<(NBUCK + 255) / 256, 256, 0, stream>>>(gcursor);
  bin_kernel<<<BIN_BLOCKS, 1024, 0, stream>>>(item_dst, item_src, h_item_val, gcursor, binned);
  sortspmm_kernel<<<NBUCK, 512, 0, stream>>>(gcursor, binned, e20, e21, grow_start, grow_cnt);
  listspmm_kernel<<<3200, 256, 0, stream>>>(grow_start, grow_cnt, binned, e21, e22, list, nlist);

  // ---- user graph
  init_cursor_kernel<<<(NBUCK + 255) / 256, 256, 0, stream>>>(gcursor);
  bin_kernel<<<BIN_BLOCKS, 1024, 0, stream>>>(user_dst, user_src, h_user_val, gcursor, binned);
  sortspmm_kernel<<<NBUCK, 512, 0, stream>>>(gcursor, binned, e30, e31, grow_start, grow_cnt);
  listspmm_kernel<<<3200, 256, 0, stream>>>(grow_start, grow_cnt, binned, e31, e32, list, nlist);

  // ---- fused acc / l2norm / attention-mix / sequence attention
  final_kernel<<<BB, 256, 0, stream>>>(input, e20, e21, e22, e30, e31, e32,
                                       att, att_m, out_Lcas, out_cas);
}

// Round 11
// 548.723 us; speedup vs baseline: 10.6473x; 1.2065x over previous
//
#include <hip/hip_runtime.h>
#include <cstdint>
#include <cstddef>

typedef unsigned short ushort_t;

#define N_NODES 100000
#define D 64
#define NNZ 3200000
#define BB 64
#define LL 200
#define BSHIFT 7
#define BSIZE 128               // nodes per bucket
#define NBUCK 782               // ceil(100000/128)
#define CAP 4608                // max edges per bucket (avg 4092, +8 sigma)
#define EPT 9                   // CAP / 512 threads (sortspmm)
#define BM_WORDS 3200           // >= ceil(100000/32)
#define BCHUNK 4096             // edges per bin block
#define BEPT 4                  // BCHUNK / 1024 threads

// ---------------------------------------------------------------- utilities
__device__ __forceinline__ float wave_sum(float x) {
#pragma unroll
  for (int o = 32; o; o >>= 1) x += __shfl_xor(x, o, 64);
  return x;
}
// bf16 (low 16 bits of arg) -> f32
__device__ __forceinline__ float bf2f(uint32_t h) {
  return __uint_as_float(h << 16);
}
// f32 -> bf16 bits (round to nearest even)
__device__ __forceinline__ uint32_t f2b(float f) {
  uint32_t u = __float_as_uint(f);
  return (u + 0x7FFFu + ((u >> 16) & 1u)) >> 16;
}

// ---------------------------------------------------------------- mark rows needed by output + compact list
__global__ void mark_kernel(const int* __restrict__ input, uint32_t* __restrict__ bm,
                            int* __restrict__ list, int* __restrict__ nlist) {
  int t = blockIdx.x * 256 + threadIdx.x;
  if (t < BB * LL) {
    int i = input[t];
    uint32_t bit = 1u << (i & 31);
    uint32_t old = atomicOr(&bm[i >> 5], bit);
    if (!(old & bit)) {
      int p = atomicAdd(nlist, 1);
      list[p] = i;
    }
  }
}

// ---------------------------------------------------------------- gate: e2 = u*sigmoid(u@w0+b0), e3 likewise
// writes fp32 (for final output path) + bf16 (for spmm gathers)
__global__ __launch_bounds__(256) void gate_kernel(
    const float* __restrict__ u, const float* __restrict__ w0,
    const float* __restrict__ w1, const float* __restrict__ b0,
    const float* __restrict__ b1, float* __restrict__ e2, float* __restrict__ e3,
    ushort_t* __restrict__ h2, ushort_t* __restrict__ h3) {
  __shared__ float sw0[D * D];
  __shared__ float sw1[D * D];
  __shared__ float sb0[D], sb1[D];
  for (int t = threadIdx.x; t < D * D; t += 256) { sw0[t] = w0[t]; sw1[t] = w1[t]; }
  if (threadIdx.x < D) { sb0[threadIdx.x] = b0[threadIdx.x]; sb1[threadIdx.x] = b1[threadIdx.x]; }
  __syncthreads();
  int wave = (blockIdx.x * 256 + threadIdx.x) >> 6;
  int lane = threadIdx.x & 63;
  int nw = (gridDim.x * 256) >> 6;
  for (int i = wave; i < N_NODES; i += nw) {
    float uv = u[i * D + lane];
    float a0 = 0.f, a1 = 0.f;
#pragma unroll
    for (int k = 0; k < D; ++k) {
      float uk = __shfl(uv, k, 64);
      a0 = fmaf(uk, sw0[k * D + lane], a0);
      a1 = fmaf(uk, sw1[k * D + lane], a1);
    }
    a0 += sb0[lane];
    a1 += sb1[lane];
    float s0 = 1.f / (1.f + expf(-a0));
    float s1 = 1.f / (1.f + expf(-a1));
    float r2 = uv * s0, r3 = uv * s1;
    e2[i * D + lane] = r2;
    e3[i * D + lane] = r3;
    h2[i * D + lane] = (ushort_t)f2b(r2);
    h3[i * D + lane] = (ushort_t)f2b(r3);
  }
}

// ---------------------------------------------------------------- bucket binning
__global__ void init_cursor_kernel(uint32_t* __restrict__ gcursor) {
  int t = blockIdx.x * 256 + threadIdx.x;
  if (t < NBUCK) gcursor[t] = (uint32_t)t * CAP;
}

// chunk of 4096 edges per block; LDS counting-sort by bucket, then COALESCED
// write-out (consecutive tid -> consecutive global addr within bucket runs).
__global__ __launch_bounds__(1024) void bin_kernel(
    const int* __restrict__ dsts, const int* __restrict__ srcs,
    const float* __restrict__ val, uint32_t* __restrict__ gcursor,
    uint2* __restrict__ binned) {
  __shared__ uint2 sp[BCHUNK];          // 32 KB bucket-sorted pairs
  __shared__ uint32_t hist[NBUCK];      // per-bucket counts (then preserved)
  __shared__ uint32_t sst[NBUCK + 1];   // exclusive bucket starts (scan)
  __shared__ uint32_t gbase[NBUCK];     // global base per bucket
  int base = blockIdx.x * BCHUNK;
  int tid = threadIdx.x;
  for (int t = tid; t < NBUCK; t += 1024) hist[t] = 0u;
  __syncthreads();
  int n = NNZ - base;
  if (n > BCHUNK) n = BCHUNK;
  uint32_t px[BEPT]; float pv[BEPT]; uint32_t pb[BEPT]; uint32_t pr[BEPT];
#pragma unroll
  for (int k = 0; k < BEPT; ++k) {
    int off = (k << 10) + tid;
    bool ok = off < n;
    int e = base + off;
    int d = ok ? dsts[e] : 0;
    int s = ok ? srcs[e] : 0;
    float v = ok ? val[e] : 0.f;
    uint32_t b = (uint32_t)d >> BSHIFT;
    pb[k] = ok ? b : 0xFFFFFFFFu;
    pr[k] = ok ? atomicAdd(&hist[b], 1u) : 0u;
    px[k] = (uint32_t)s | ((uint32_t)(d & (BSIZE - 1)) << 17);
    pv[k] = v;
  }
  __syncthreads();
  // gbase atomics (independent of scan) + seed scan array: sst[i+1] = hist[i]
  for (int t = tid; t < NBUCK; t += 1024) {
    uint32_t h = hist[t];
    gbase[t] = h ? atomicAdd(&gcursor[t], h) : 0u;
    sst[t + 1] = h;
  }
  if (tid == 0) sst[0] = 0u;
  __syncthreads();
  // inclusive scan over sst[1..NBUCK] (Hillis-Steele; element i = tid+1)
  for (int o = 1; o < NBUCK; o <<= 1) {
    uint32_t t = 0u;
    if (tid < NBUCK && (int)(tid + 1) > o) t = sst[tid + 1 - o];
    __syncthreads();
    if (tid < NBUCK && (int)(tid + 1) > o) sst[tid + 1] += t;
    __syncthreads();
  }
  // scatter into bucket-sorted LDS
#pragma unroll
  for (int k = 0; k < BEPT; ++k) {
    if (pb[k] != 0xFFFFFFFFu)
      sp[sst[pb[k]] + pr[k]] = make_uint2(px[k], __float_as_uint(pv[k]));
  }
  __syncthreads();
  // coalesced write-out: find bucket of idx by binary search over sst
  for (int idx = tid; idx < n; idx += 1024) {
    int lo = 0, hi = NBUCK;  // invariant: sst[lo] <= idx < sst[hi]
    while (hi - lo > 1) {
      int mid = (lo + hi) >> 1;
      if ((int)sst[mid] <= idx) lo = mid; else hi = mid;
    }
    uint32_t pos = gbase[lo] + ((uint32_t)idx - sst[lo]);
    if (pos < (uint32_t)(lo + 1) * CAP) {  // overflow guard
      binned[pos] = sp[idx];
    }
  }
}

// ---------------------------------------------------------------- sort + spmm (layer 1)
// One block per bucket. In-LDS counting sort by local row, then wave-per-row
// gather in 32-edge chunks: 8 independent bf16 gathers in flight per wave,
// fp32 register accumulation, bf16 output (feeds layer 2 + final's l2norm).
__global__ __launch_bounds__(512) void sortspmm_kernel(
    const uint32_t* __restrict__ gcursor, uint2* __restrict__ binned,
    const ushort_t* __restrict__ xin, ushort_t* __restrict__ xout,
    uint32_t* __restrict__ grow_start, uint32_t* __restrict__ grow_cnt) {
  __shared__ uint2 sp[CAP];           // 36864 B sorted pairs
  __shared__ uint32_t hist[BSIZE];    // per-row counts
  __shared__ uint32_t ssc[BSIZE];     // scan buffer
  __shared__ uint32_t sst[BSIZE];     // exclusive row starts
  int bucket = blockIdx.x, tid = threadIdx.x;
  int nodebase = bucket << BSHIFT;
  uint32_t cnt = gcursor[bucket] - (uint32_t)bucket * CAP;
  if (cnt > CAP) cnt = CAP;
  if (tid < BSIZE) hist[tid] = 0u;
  __syncthreads();
  // load edges to registers + rank within row via LDS atomic (128 counters)
  uint2 pr[EPT]; uint32_t rk[EPT];
  const uint2* ep = binned + (size_t)bucket * CAP;
#pragma unroll
  for (int k = 0; k < EPT; ++k) {
    int e = (k << 9) + tid;
    if (e < (int)cnt) {
      pr[k] = ep[e];
      rk[k] = atomicAdd(&hist[pr[k].x >> 17], 1u);
    }
  }
  __syncthreads();
  // inclusive scan of 128 counts (Hillis-Steele, uniform barriers)
  if (tid < BSIZE) ssc[tid] = hist[tid];
  __syncthreads();
  for (int o = 1; o < BSIZE; o <<= 1) {
    uint32_t t = 0;
    if (tid < BSIZE && tid >= o) t = ssc[tid - o];
    __syncthreads();
    if (tid < BSIZE) ssc[tid] += t;
    __syncthreads();
  }
  if (tid < BSIZE) sst[tid] = ssc[tid] - hist[tid];
  __syncthreads();
  // scatter into row-sorted LDS array
#pragma unroll
  for (int k = 0; k < EPT; ++k) {
    int e = (k << 9) + tid;
    if (e < (int)cnt) sp[sst[pr[k].x >> 17] + rk[k]] = pr[k];
  }
  __syncthreads();
  // write back sorted pairs + row meta (consumed by the layer-2 list pass)
  for (int t = tid; t < (int)cnt; t += 512) binned[(size_t)bucket * CAP + t] = sp[t];
  int nvalid = N_NODES - nodebase;
  if (nvalid > BSIZE) nvalid = BSIZE;
  if (tid < nvalid) {
    grow_start[nodebase + tid] = (uint32_t)bucket * CAP + sst[tid];
    grow_cnt[nodebase + tid] = hist[tid];
  }
  // wave-per-row spmm: lane = g*16+c; 32-edge chunks, 8 gathers in flight
  int wave = tid >> 6, lane = tid & 63, g = lane >> 4, c = lane & 15;
  for (int r = wave; r < nvalid; r += 8) {
    uint32_t rc = hist[r], s0 = sst[r];
    float ax = 0.f, ay = 0.f, az = 0.f, aw = 0.f;
    for (uint32_t j0 = 0; j0 < rc; j0 += 32) {
      uint2 pk[8];
#pragma unroll
      for (int k = 0; k < 8; ++k) {
        uint32_t e = j0 + (uint32_t)g + (uint32_t)(k << 2);
        pk[k] = (e < rc) ? sp[s0 + e] : make_uint2(0u, 0u);
      }
      uint2 qk[8];
#pragma unroll
      for (int k = 0; k < 8; ++k) {
        uint32_t src = pk[k].x & 0x1FFFFu;
        qk[k] = ((const uint2*)(xin + (size_t)src * D))[c];  // 4 bf16 cols
      }
#pragma unroll
      for (int k = 0; k < 8; ++k) {
        float v = __uint_as_float(pk[k].y);
        ax = fmaf(v, bf2f(qk[k].x & 0xFFFFu), ax);
        ay = fmaf(v, bf2f(qk[k].x >> 16), ay);
        az = fmaf(v, bf2f(qk[k].y & 0xFFFFu), az);
        aw = fmaf(v, bf2f(qk[k].y >> 16), aw);
      }
    }
#pragma unroll
    for (int o = 16; o <= 32; o <<= 1) {
      ax += __shfl_xor(ax, o, 64); ay += __shfl_xor(ay, o, 64);
      az += __shfl_xor(az, o, 64); aw += __shfl_xor(aw, o, 64);
    }
    if (g == 0) {
      uint32_t lo = f2b(ax) | (f2b(ay) << 16);
      uint32_t hi = f2b(az) | (f2b(aw) << 16);
      ((uint2*)(xout + (size_t)(nodebase + r) * D))[c] = make_uint2(lo, hi);
    }
  }
}

// ---------------------------------------------------------------- layer-2 spmm over marked rows only
// bf16 gather, fp32 output (terminal — consumed only by final_kernel)
__global__ __launch_bounds__(256) void listspmm_kernel(
    const uint32_t* __restrict__ grow_start, const uint32_t* __restrict__ grow_cnt,
    const uint2* __restrict__ pairs, const ushort_t* __restrict__ xin,
    float* __restrict__ xout, const int* __restrict__ list, const int* __restrict__ nlist) {
  int wave = (blockIdx.x * 256 + threadIdx.x) >> 6;
  int lane = threadIdx.x & 63;
  int nw = (gridDim.x * 256) >> 6;
  int g = lane >> 4, c = lane & 15;
  int n = nlist[0];
  for (int ii = wave; ii < n; ii += nw) {
    int i = list[ii];
    uint32_t rc = grow_cnt[i];
    uint32_t base = grow_start[i];
    float ax = 0.f, ay = 0.f, az = 0.f, aw = 0.f;
    for (uint32_t j0 = 0; j0 < rc; j0 += 32) {
      uint2 pk[8];
#pragma unroll
      for (int k = 0; k < 8; ++k) {
        uint32_t e = j0 + (uint32_t)g + (uint32_t)(k << 2);
        pk[k] = (e < rc) ? pairs[base + e] : make_uint2(0u, 0u);
      }
      uint2 qk[8];
#pragma unroll
      for (int k = 0; k < 8; ++k) {
        uint32_t src = pk[k].x & 0x1FFFFu;
        qk[k] = ((const uint2*)(xin + (size_t)src * D))[c];
      }
#pragma unroll
      for (int k = 0; k < 8; ++k) {
        float v = __uint_as_float(pk[k].y);
        ax = fmaf(v, bf2f(qk[k].x & 0xFFFFu), ax);
        ay = fmaf(v, bf2f(qk[k].x >> 16), ay);
        az = fmaf(v, bf2f(qk[k].y & 0xFFFFu), az);
        aw = fmaf(v, bf2f(qk[k].y >> 16), aw);
      }
    }
#pragma unroll
    for (int o = 16; o <= 32; o <<= 1) {
      ax += __shfl_xor(ax, o, 64); ay += __shfl_xor(ay, o, 64);
      az += __shfl_xor(az, o, 64); aw += __shfl_xor(aw, o, 64);
    }
    if (g == 0)
      ((float4*)(xout + (size_t)i * D))[c] = make_float4(ax, ay, az, aw);
  }
}

// ---------------------------------------------------------------- final: fused acc/l2norm/mix + seq attention
__global__ __launch_bounds__(256) void final_kernel(
    const int* __restrict__ input,
    const float* __restrict__ e20, const ushort_t* __restrict__ h21, const float* __restrict__ e22,
    const float* __restrict__ e30, const ushort_t* __restrict__ h31, const float* __restrict__ e32,
    const float* __restrict__ att, const float* __restrict__ att_m,
    float* __restrict__ out_Lcas, float* __restrict__ out_cas) {
  __shared__ float cas[LL * D];  // 51.2 KB
  __shared__ float sv[D];
  __shared__ float sscore[LL];
  __shared__ float red[8];
  int b = blockIdx.x, tid = threadIdx.x;
  if (tid < D) {
    float a = 0.f;
#pragma unroll
    for (int j = 0; j < D; ++j) a = fmaf(att_m[tid * D + j], att[j], a);
    sv[tid] = a;
  }
  __syncthreads();
  int wv = tid >> 6, lane = tid & 63;
  float svl = sv[lane];
  for (int l = wv; l < LL; l += 4) {
    int i = input[b * LL + l];
    size_t o = (size_t)i * D + lane;
    float v20 = e20[o], v22 = e22[o];
    float v30 = e30[o], v32 = e32[o];
    float v21 = bf2f((uint32_t)h21[o]);
    float v31 = bf2f((uint32_t)h31[o]);
    float n21 = fmaxf(sqrtf(wave_sum(v21 * v21)), 1e-12f);
    float n22 = fmaxf(sqrtf(wave_sum(v22 * v22)), 1e-12f);
    float n31 = fmaxf(sqrtf(wave_sum(v31 * v31)), 1e-12f);
    float n32 = fmaxf(sqrtf(wave_sum(v32 * v32)), 1e-12f);
    float a2 = v20 + v21 / n21 + v22 / n22;
    float a3 = v30 + v31 / n31 + v32 / n32;
    float w2 = wave_sum(a2 * svl);
    float w3 = wave_sum(a3 * svl);
    float mx = fmaxf(w2, w3);
    float ex2 = expf(w2 - mx), ex3 = expf(w3 - mx);
    float inv = 1.f / (ex2 + ex3);
    float mix = (ex2 * a2 + ex3 * a3) * inv;
    cas[l * D + lane] = mix;
    out_cas[(size_t)(b * LL + l) * D + lane] = mix;
  }
  __syncthreads();
  for (int l = wv; l < LL; l += 4) {
    float s = wave_sum(cas[lane] * cas[l * D + lane]) * 0.125f;  // 1/sqrt(64)
    int iv = input[b * LL + l];
    s = (iv == 0) ? -1e9f : s;
    if (lane == 0) sscore[l] = s;
  }
  __syncthreads();
  float m = -INFINITY;
  for (int l = tid; l < LL; l += 256) m = fmaxf(m, sscore[l]);
#pragma unroll
  for (int o = 32; o; o >>= 1) m = fmaxf(m, __shfl_xor(m, o, 64));
  if (lane == 0) red[wv] = m;
  __syncthreads();
  m = fmaxf(fmaxf(red[0], red[1]), fmaxf(red[2], red[3]));
  float sum = 0.f;
  for (int l = tid; l < LL; l += 256) sum += expf(sscore[l] - m);
  sum = wave_sum(sum);
  if (lane == 0) red[4 + wv] = sum;
  __syncthreads();
  float inv = 1.f / (red[4] + red[5] + red[6] + red[7]);
  for (int l = tid; l < LL; l += 256) sscore[l] = expf(sscore[l] - m) * inv;
  __syncthreads();
  for (int t = tid; t < LL * D; t += 256)
    out_Lcas[(size_t)b * LL * D + t] = sscore[t >> 6] * cas[t];
}

// ---------------------------------------------------------------- launch
extern "C" void kernel_launch(void* const* d_in, const int* in_sizes, int n_in,
                              void* d_out, int out_size, void* d_ws, size_t ws_size,
                              hipStream_t stream) {
  const int* input = (const int*)d_in[0];
  const int* h_item_idx = (const int*)d_in[1];
  const float* h_item_val = (const float*)d_in[2];
  const int* h_user_idx = (const int*)d_in[3];
  const float* h_user_val = (const float*)d_in[4];
  const float* user_emb = (const float*)d_in[5];
  const float* w0 = (const float*)d_in[6];
  const float* w1 = (const float*)d_in[7];
  const float* b0 = (const float*)d_in[8];
  const float* b1 = (const float*)d_in[9];
  const float* att = (const float*)d_in[10];
  const float* att_m = (const float*)d_in[11];

  float* out = (float*)d_out;
  float* out_Lcas = out;                       // B*L*D
  float* out_cas = out + (size_t)BB * LL * D;  // B*L*D

  const size_t ND = (size_t)N_NODES * D;  // 6.4M elements
  char* ws = (char*)d_ws;
  float* e20 = (float*)ws; ws += ND * 4;
  float* e30 = (float*)ws; ws += ND * 4;
  float* e22 = (float*)ws; ws += ND * 4;
  float* e32 = (float*)ws; ws += ND * 4;
  ushort_t* h20 = (ushort_t*)ws; ws += ND * 2;
  ushort_t* h30 = (ushort_t*)ws; ws += ND * 2;
  ushort_t* h21 = (ushort_t*)ws; ws += ND * 2;
  ushort_t* h31 = (ushort_t*)ws; ws += ND * 2;
  uint2* binned = (uint2*)ws; ws += (size_t)NBUCK * CAP * 8;  // 28.8 MB
  uint32_t* gcursor = (uint32_t*)ws; ws += (size_t)((NBUCK + 63) & ~63) * 4;
  uint32_t* bitmap = (uint32_t*)ws; ws += (size_t)BM_WORDS * 4;
  uint32_t* grow_start = (uint32_t*)ws; ws += (size_t)N_NODES * 4;
  uint32_t* grow_cnt = (uint32_t*)ws; ws += (size_t)N_NODES * 4;
  int* list = (int*)ws; ws += (size_t)(BB * LL) * 4;
  int* nlist = (int*)ws; ws += 64;

  const int* item_dst = h_item_idx;
  const int* item_src = h_item_idx + NNZ;
  const int* user_dst = h_user_idx;
  const int* user_src = h_user_idx + NNZ;

  const int BIN_BLOCKS = (NNZ + BCHUNK - 1) / BCHUNK;  // 782

  // bitmap + compact list of rows actually needed by the output gather
  hipMemsetAsync(bitmap, 0, (size_t)BM_WORDS * 4, stream);
  hipMemsetAsync(nlist, 0, 64, stream);
  mark_kernel<<<(BB * LL + 255) / 256, 256, 0, stream>>>(input, bitmap, list, nlist);

  // gate (fp32 + bf16 outputs)
  gate_kernel<<<2048, 256, 0, stream>>>(user_emb, w0, w1, b0, b1, e20, e30, h20, h30);

  // ---- item graph: bin -> sort+spmm layer1 (bf16 gather) -> list spmm layer2
  init_cursor_kernel<<<(NBUCK + 255) / 256, 256, 0, stream>>>(gcursor);
  bin_kernel<<<BIN_BLOCKS, 1024, 0, stream>>>(item_dst, item_src, h_item_val, gcursor, binned);
  sortspmm_kernel<<<NBUCK, 512, 0, stream>>>(gcursor, binned, h20, h21, grow_start, grow_cnt);
  listspmm_kernel<<<3200, 256, 0, stream>>>(grow_start, grow_cnt, binned, h21, e22, list, nlist);

  // ---- user graph
  init_cursor_kernel<<<(NBUCK + 255) / 256, 256, 0, stream>>>(gcursor);
  bin_kernel<<<BIN_BLOCKS, 1024, 0, stream>>>(user_dst, user_src, h_user_val, gcursor, binned);
  sortspmm_kernel<<<NBUCK, 512, 0, stream>>>(gcursor, binned, h30, h31, grow_start, grow_cnt);
  listspmm_kernel<<<3200, 256, 0, stream>>>(grow_start, grow_cnt, binned, h31, e32, list, nlist);

  // ---- fused acc / l2norm / attention-mix / sequence attention
  final_kernel<<<BB, 256, 0, stream>>>(input, e20, h21, e22, e30, h31, e32,
                                       att, att_m, out_Lcas, out_cas);
}

// Round 13
// 544.957 us; speedup vs baseline: 10.7209x; 1.0069x over previous
//
#include <hip/hip_runtime.h>
#include <cstdint>
#include <cstddef>

typedef unsigned short ushort_t;

#define N_NODES 100000
#define D 64
#define NNZ 3200000
#define BB 64
#define LL 200
#define BSHIFT 7
#define BSIZE 128               // nodes per bucket
#define NBUCK 782               // ceil(100000/128)
#define CAP 4608                // max edges per bucket (avg 4092, +8 sigma)
#define EPT 9                   // CAP / 512 threads (sortspmm)
#define BM_WORDS 3200           // >= ceil(100000/32)
#define BCHUNK 4096             // edges per bin block
#define BEPT 4                  // BCHUNK / 1024 threads

// ---------------------------------------------------------------- utilities
__device__ __forceinline__ float wave_sum(float x) {
#pragma unroll
  for (int o = 32; o; o >>= 1) x += __shfl_xor(x, o, 64);
  return x;
}
// bf16 (low 16 bits of arg) -> f32
__device__ __forceinline__ float bf2f(uint32_t h) {
  return __uint_as_float(h << 16);
}
// f32 -> bf16 bits (round to nearest even)
__device__ __forceinline__ uint32_t f2b(float f) {
  uint32_t u = __float_as_uint(f);
  return (u + 0x7FFFu + ((u >> 16) & 1u)) >> 16;
}

// ---------------------------------------------------------------- mark rows needed by output + compact list
__global__ void mark_kernel(const int* __restrict__ input, uint32_t* __restrict__ bm,
                            int* __restrict__ list, int* __restrict__ nlist) {
  int t = blockIdx.x * 256 + threadIdx.x;
  if (t < BB * LL) {
    int i = input[t];
    uint32_t bit = 1u << (i & 31);
    uint32_t old = atomicOr(&bm[i >> 5], bit);
    if (!(old & bit)) {
      int p = atomicAdd(nlist, 1);
      list[p] = i;
    }
  }
}

// ---------------------------------------------------------------- gate: h2 = bf16(u*sigmoid(u@w0+b0)), h3 likewise
// W0,W1 packed as bf16 pairs in LDS (one read serves both); 4 rows per wave
// iteration (8 independent accumulators); bf16-only output.
__global__ __launch_bounds__(256) void gate_kernel(
    const float* __restrict__ u, const float* __restrict__ w0,
    const float* __restrict__ w1, const float* __restrict__ b0,
    const float* __restrict__ b1,
    ushort_t* __restrict__ h2, ushort_t* __restrict__ h3) {
  __shared__ uint32_t sw01[D * D];   // 16 KB: (bf16 w0 | bf16 w1 << 16)
  __shared__ float sb0[D], sb1[D];
  for (int t = threadIdx.x; t < D * D; t += 256)
    sw01[t] = f2b(w0[t]) | (f2b(w1[t]) << 16);
  if (threadIdx.x < D) { sb0[threadIdx.x] = b0[threadIdx.x]; sb1[threadIdx.x] = b1[threadIdx.x]; }
  __syncthreads();
  int wave = (blockIdx.x * 256 + threadIdx.x) >> 6;
  int lane = threadIdx.x & 63;
  int nw = (gridDim.x * 256) >> 6;
  const int NT = N_NODES >> 2;  // 25000 four-row tiles (100000 % 4 == 0)
  for (int t = wave; t < NT; t += nw) {
    int row = t << 2;
    float uv0 = u[(size_t)(row + 0) * D + lane];
    float uv1 = u[(size_t)(row + 1) * D + lane];
    float uv2 = u[(size_t)(row + 2) * D + lane];
    float uv3 = u[(size_t)(row + 3) * D + lane];
    float a00 = 0.f, a01 = 0.f, a02 = 0.f, a03 = 0.f;
    float a10 = 0.f, a11 = 0.f, a12 = 0.f, a13 = 0.f;
#pragma unroll 16
    for (int k = 0; k < D; ++k) {
      uint32_t wp = sw01[k * D + lane];
      float wa = bf2f(wp & 0xFFFFu);
      float wb = bf2f(wp >> 16);
      float u0 = __shfl(uv0, k, 64);
      float u1 = __shfl(uv1, k, 64);
      float u2 = __shfl(uv2, k, 64);
      float u3 = __shfl(uv3, k, 64);
      a00 = fmaf(u0, wa, a00); a10 = fmaf(u0, wb, a10);
      a01 = fmaf(u1, wa, a01); a11 = fmaf(u1, wb, a11);
      a02 = fmaf(u2, wa, a02); a12 = fmaf(u2, wb, a12);
      a03 = fmaf(u3, wa, a03); a13 = fmaf(u3, wb, a13);
    }
    float bb0 = sb0[lane], bb1 = sb1[lane];
    float s;
    s = 1.f / (1.f + expf(-(a00 + bb0))); h2[(size_t)(row + 0) * D + lane] = (ushort_t)f2b(uv0 * s);
    s = 1.f / (1.f + expf(-(a01 + bb0))); h2[(size_t)(row + 1) * D + lane] = (ushort_t)f2b(uv1 * s);
    s = 1.f / (1.f + expf(-(a02 + bb0))); h2[(size_t)(row + 2) * D + lane] = (ushort_t)f2b(uv2 * s);
    s = 1.f / (1.f + expf(-(a03 + bb0))); h2[(size_t)(row + 3) * D + lane] = (ushort_t)f2b(uv3 * s);
    s = 1.f / (1.f + expf(-(a10 + bb1))); h3[(size_t)(row + 0) * D + lane] = (ushort_t)f2b(uv0 * s);
    s = 1.f / (1.f + expf(-(a11 + bb1))); h3[(size_t)(row + 1) * D + lane] = (ushort_t)f2b(uv1 * s);
    s = 1.f / (1.f + expf(-(a12 + bb1))); h3[(size_t)(row + 2) * D + lane] = (ushort_t)f2b(uv2 * s);
    s = 1.f / (1.f + expf(-(a13 + bb1))); h3[(size_t)(row + 3) * D + lane] = (ushort_t)f2b(uv3 * s);
  }
}

// ---------------------------------------------------------------- bucket binning
__global__ void init_cursor_kernel(uint32_t* __restrict__ gcursor) {
  int t = blockIdx.x * 256 + threadIdx.x;
  if (t < NBUCK) gcursor[t] = (uint32_t)t * CAP;
}

// chunk of 4096 edges per block; LDS counting-sort by bucket, then COALESCED
// write-out (consecutive tid -> consecutive global addr within bucket runs).
__global__ __launch_bounds__(1024) void bin_kernel(
    const int* __restrict__ dsts, const int* __restrict__ srcs,
    const float* __restrict__ val, uint32_t* __restrict__ gcursor,
    uint2* __restrict__ binned) {
  __shared__ uint2 sp[BCHUNK];          // 32 KB bucket-sorted pairs
  __shared__ uint32_t hist[NBUCK];      // per-bucket counts (then preserved)
  __shared__ uint32_t sst[NBUCK + 1];   // exclusive bucket starts (scan)
  __shared__ uint32_t gbase[NBUCK];     // global base per bucket
  int base = blockIdx.x * BCHUNK;
  int tid = threadIdx.x;
  for (int t = tid; t < NBUCK; t += 1024) hist[t] = 0u;
  __syncthreads();
  int n = NNZ - base;
  if (n > BCHUNK) n = BCHUNK;
  uint32_t px[BEPT]; float pv[BEPT]; uint32_t pb[BEPT]; uint32_t pr[BEPT];
#pragma unroll
  for (int k = 0; k < BEPT; ++k) {
    int off = (k << 10) + tid;
    bool ok = off < n;
    int e = base + off;
    int d = ok ? dsts[e] : 0;
    int s = ok ? srcs[e] : 0;
    float v = ok ? val[e] : 0.f;
    uint32_t b = (uint32_t)d >> BSHIFT;
    pb[k] = ok ? b : 0xFFFFFFFFu;
    pr[k] = ok ? atomicAdd(&hist[b], 1u) : 0u;
    px[k] = (uint32_t)s | ((uint32_t)(d & (BSIZE - 1)) << 17);
    pv[k] = v;
  }
  __syncthreads();
  // gbase atomics (independent of scan) + seed scan array: sst[i+1] = hist[i]
  for (int t = tid; t < NBUCK; t += 1024) {
    uint32_t h = hist[t];
    gbase[t] = h ? atomicAdd(&gcursor[t], h) : 0u;
    sst[t + 1] = h;
  }
  if (tid == 0) sst[0] = 0u;
  __syncthreads();
  // inclusive scan over sst[1..NBUCK] (Hillis-Steele; element i = tid+1)
  for (int o = 1; o < NBUCK; o <<= 1) {
    uint32_t t = 0u;
    if (tid < NBUCK && (int)(tid + 1) > o) t = sst[tid + 1 - o];
    __syncthreads();
    if (tid < NBUCK && (int)(tid + 1) > o) sst[tid + 1] += t;
    __syncthreads();
  }
  // scatter into bucket-sorted LDS
#pragma unroll
  for (int k = 0; k < BEPT; ++k) {
    if (pb[k] != 0xFFFFFFFFu)
      sp[sst[pb[k]] + pr[k]] = make_uint2(px[k], __float_as_uint(pv[k]));
  }
  __syncthreads();
  // coalesced write-out: find bucket of idx by binary search over sst
  for (int idx = tid; idx < n; idx += 1024) {
    int lo = 0, hi = NBUCK;  // invariant: sst[lo] <= idx < sst[hi]
    while (hi - lo > 1) {
      int mid = (lo + hi) >> 1;
      if ((int)sst[mid] <= idx) lo = mid; else hi = mid;
    }
    uint32_t pos = gbase[lo] + ((uint32_t)idx - sst[lo]);
    if (pos < (uint32_t)(lo + 1) * CAP) {  // overflow guard
      binned[pos] = sp[idx];
    }
  }
}

// ---------------------------------------------------------------- sort + spmm (layer 1)
// One block per bucket. In-LDS counting sort by local row, then wave-per-row
// gather in 32-edge chunks: 8 independent bf16 gathers in flight per wave,
// fp32 register accumulation, bf16 output (feeds layer 2 + final's l2norm).
__global__ __launch_bounds__(512) void sortspmm_kernel(
    const uint32_t* __restrict__ gcursor, uint2* __restrict__ binned,
    const ushort_t* __restrict__ xin, ushort_t* __restrict__ xout,
    uint32_t* __restrict__ grow_start, uint32_t* __restrict__ grow_cnt) {
  __shared__ uint2 sp[CAP];           // 36864 B sorted pairs
  __shared__ uint32_t hist[BSIZE];    // per-row counts
  __shared__ uint32_t ssc[BSIZE];     // scan buffer
  __shared__ uint32_t sst[BSIZE];     // exclusive row starts
  int bucket = blockIdx.x, tid = threadIdx.x;
  int nodebase = bucket << BSHIFT;
  uint32_t cnt = gcursor[bucket] - (uint32_t)bucket * CAP;
  if (cnt > CAP) cnt = CAP;
  if (tid < BSIZE) hist[tid] = 0u;
  __syncthreads();
  // load edges to registers + rank within row via LDS atomic (128 counters)
  uint2 pr[EPT]; uint32_t rk[EPT];
  const uint2* ep = binned + (size_t)bucket * CAP;
#pragma unroll
  for (int k = 0; k < EPT; ++k) {
    int e = (k << 9) + tid;
    if (e < (int)cnt) {
      pr[k] = ep[e];
      rk[k] = atomicAdd(&hist[pr[k].x >> 17], 1u);
    }
  }
  __syncthreads();
  // inclusive scan of 128 counts (Hillis-Steele, uniform barriers)
  if (tid < BSIZE) ssc[tid] = hist[tid];
  __syncthreads();
  for (int o = 1; o < BSIZE; o <<= 1) {
    uint32_t t = 0;
    if (tid < BSIZE && tid >= o) t = ssc[tid - o];
    __syncthreads();
    if (tid < BSIZE) ssc[tid] += t;
    __syncthreads();
  }
  if (tid < BSIZE) sst[tid] = ssc[tid] - hist[tid];
  __syncthreads();
  // scatter into row-sorted LDS array
#pragma unroll
  for (int k = 0; k < EPT; ++k) {
    int e = (k << 9) + tid;
    if (e < (int)cnt) sp[sst[pr[k].x >> 17] + rk[k]] = pr[k];
  }
  __syncthreads();
  // write back sorted pairs + row meta (consumed by the layer-2 list pass)
  for (int t = tid; t < (int)cnt; t += 512) binned[(size_t)bucket * CAP + t] = sp[t];
  int nvalid = N_NODES - nodebase;
  if (nvalid > BSIZE) nvalid = BSIZE;
  if (tid < nvalid) {
    grow_start[nodebase + tid] = (uint32_t)bucket * CAP + sst[tid];
    grow_cnt[nodebase + tid] = hist[tid];
  }
  // wave-per-row spmm: lane = g*16+c; 32-edge chunks, 8 gathers in flight
  int wave = tid >> 6, lane = tid & 63, g = lane >> 4, c = lane & 15;
  for (int r = wave; r < nvalid; r += 8) {
    uint32_t rc = hist[r], s0 = sst[r];
    float ax = 0.f, ay = 0.f, az = 0.f, aw = 0.f;
    for (uint32_t j0 = 0; j0 < rc; j0 += 32) {
      uint2 pk[8];
#pragma unroll
      for (int k = 0; k < 8; ++k) {
        uint32_t e = j0 + (uint32_t)g + (uint32_t)(k << 2);
        pk[k] = (e < rc) ? sp[s0 + e] : make_uint2(0u, 0u);
      }
      uint2 qk[8];
#pragma unroll
      for (int k = 0; k < 8; ++k) {
        uint32_t src = pk[k].x & 0x1FFFFu;
        qk[k] = ((const uint2*)(xin + (size_t)src * D))[c];  // 4 bf16 cols
      }
#pragma unroll
      for (int k = 0; k < 8; ++k) {
        float v = __uint_as_float(pk[k].y);
        ax = fmaf(v, bf2f(qk[k].x & 0xFFFFu), ax);
        ay = fmaf(v, bf2f(qk[k].x >> 16), ay);
        az = fmaf(v, bf2f(qk[k].y & 0xFFFFu), az);
        aw = fmaf(v, bf2f(qk[k].y >> 16), aw);
      }
    }
#pragma unroll
    for (int o = 16; o <= 32; o <<= 1) {
      ax += __shfl_xor(ax, o, 64); ay += __shfl_xor(ay, o, 64);
      az += __shfl_xor(az, o, 64); aw += __shfl_xor(aw, o, 64);
    }
    if (g == 0) {
      uint32_t lo = f2b(ax) | (f2b(ay) << 16);
      uint32_t hi = f2b(az) | (f2b(aw) << 16);
      ((uint2*)(xout + (size_t)(nodebase + r) * D))[c] = make_uint2(lo, hi);
    }
  }
}

// ---------------------------------------------------------------- layer-2 spmm over marked rows only
// bf16 gather, fp32 output (terminal — consumed only by final_kernel)
__global__ __launch_bounds__(256) void listspmm_kernel(
    const uint32_t* __restrict__ grow_start, const uint32_t* __restrict__ grow_cnt,
    const uint2* __restrict__ pairs, const ushort_t* __restrict__ xin,
    float* __restrict__ xout, const int* __restrict__ list, const int* __restrict__ nlist) {
  int wave = (blockIdx.x * 256 + threadIdx.x) >> 6;
  int lane = threadIdx.x & 63;
  int nw = (gridDim.x * 256) >> 6;
  int g = lane >> 4, c = lane & 15;
  int n = nlist[0];
  for (int ii = wave; ii < n; ii += nw) {
    int i = list[ii];
    uint32_t rc = grow_cnt[i];
    uint32_t base = grow_start[i];
    float ax = 0.f, ay = 0.f, az = 0.f, aw = 0.f;
    for (uint32_t j0 = 0; j0 < rc; j0 += 32) {
      uint2 pk[8];
#pragma unroll
      for (int k = 0; k < 8; ++k) {
        uint32_t e = j0 + (uint32_t)g + (uint32_t)(k << 2);
        pk[k] = (e < rc) ? pairs[base + e] : make_uint2(0u, 0u);
      }
      uint2 qk[8];
#pragma unroll
      for (int k = 0; k < 8; ++k) {
        uint32_t src = pk[k].x & 0x1FFFFu;
        qk[k] = ((const uint2*)(xin + (size_t)src * D))[c];
      }
#pragma unroll
      for (int k = 0; k < 8; ++k) {
        float v = __uint_as_float(pk[k].y);
        ax = fmaf(v, bf2f(qk[k].x & 0xFFFFu), ax);
        ay = fmaf(v, bf2f(qk[k].x >> 16), ay);
        az = fmaf(v, bf2f(qk[k].y & 0xFFFFu), az);
        aw = fmaf(v, bf2f(qk[k].y >> 16), aw);
      }
    }
#pragma unroll
    for (int o = 16; o <= 32; o <<= 1) {
      ax += __shfl_xor(ax, o, 64); ay += __shfl_xor(ay, o, 64);
      az += __shfl_xor(az, o, 64); aw += __shfl_xor(aw, o, 64);
    }
    if (g == 0)
      ((float4*)(xout + (size_t)i * D))[c] = make_float4(ax, ay, az, aw);
  }
}

// ---------------------------------------------------------------- final: fused acc/l2norm/mix + seq attention
__global__ __launch_bounds__(256) void final_kernel(
    const int* __restrict__ input,
    const ushort_t* __restrict__ h20, const ushort_t* __restrict__ h21, const float* __restrict__ e22,
    const ushort_t* __restrict__ h30, const ushort_t* __restrict__ h31, const float* __restrict__ e32,
    const float* __restrict__ att, const float* __restrict__ att_m,
    float* __restrict__ out_Lcas, float* __restrict__ out_cas) {
  __shared__ float cas[LL * D];  // 51.2 KB
  __shared__ float sv[D];
  __shared__ float sscore[LL];
  __shared__ float red[8];
  int b = blockIdx.x, tid = threadIdx.x;
  if (tid < D) {
    float a = 0.f;
#pragma unroll
    for (int j = 0; j < D; ++j) a = fmaf(att_m[tid * D + j], att[j], a);
    sv[tid] = a;
  }
  __syncthreads();
  int wv = tid >> 6, lane = tid & 63;
  float svl = sv[lane];
  for (int l = wv; l < LL; l += 4) {
    int i = input[b * LL + l];
    size_t o = (size_t)i * D + lane;
    float v20 = bf2f((uint32_t)h20[o]), v22 = e22[o];
    float v30 = bf2f((uint32_t)h30[o]), v32 = e32[o];
    float v21 = bf2f((uint32_t)h21[o]);
    float v31 = bf2f((uint32_t)h31[o]);
    float n21 = fmaxf(sqrtf(wave_sum(v21 * v21)), 1e-12f);
    float n22 = fmaxf(sqrtf(wave_sum(v22 * v22)), 1e-12f);
    float n31 = fmaxf(sqrtf(wave_sum(v31 * v31)), 1e-12f);
    float n32 = fmaxf(sqrtf(wave_sum(v32 * v32)), 1e-12f);
    float a2 = v20 + v21 / n21 + v22 / n22;
    float a3 = v30 + v31 / n31 + v32 / n32;
    float w2 = wave_sum(a2 * svl);
    float w3 = wave_sum(a3 * svl);
    float mx = fmaxf(w2, w3);
    float ex2 = expf(w2 - mx), ex3 = expf(w3 - mx);
    float inv = 1.f / (ex2 + ex3);
    float mix = (ex2 * a2 + ex3 * a3) * inv;
    cas[l * D + lane] = mix;
    out_cas[(size_t)(b * LL + l) * D + lane] = mix;
  }
  __syncthreads();
  for (int l = wv; l < LL; l += 4) {
    float s = wave_sum(cas[lane] * cas[l * D + lane]) * 0.125f;  // 1/sqrt(64)
    int iv = input[b * LL + l];
    s = (iv == 0) ? -1e9f : s;
    if (lane == 0) sscore[l] = s;
  }
  __syncthreads();
  float m = -INFINITY;
  for (int l = tid; l < LL; l += 256) m = fmaxf(m, sscore[l]);
#pragma unroll
  for (int o = 32; o; o >>= 1) m = fmaxf(m, __shfl_xor(m, o, 64));
  if (lane == 0) red[wv] = m;
  __syncthreads();
  m = fmaxf(fmaxf(red[0], red[1]), fmaxf(red[2], red[3]));
  float sum = 0.f;
  for (int l = tid; l < LL; l += 256) sum += expf(sscore[l] - m);
  sum = wave_sum(sum);
  if (lane == 0) red[4 + wv] = sum;
  __syncthreads();
  float inv = 1.f / (red[4] + red[5] + red[6] + red[7]);
  for (int l = tid; l < LL; l += 256) sscore[l] = expf(sscore[l] - m) * inv;
  __syncthreads();
  for (int t = tid; t < LL * D; t += 256)
    out_Lcas[(size_t)b * LL * D + t] = sscore[t >> 6] * cas[t];
}

// ---------------------------------------------------------------- launch
extern "C" void kernel_launch(void* const* d_in, const int* in_sizes, int n_in,
                              void* d_out, int out_size, void* d_ws, size_t ws_size,
                              hipStream_t stream) {
  const int* input = (const int*)d_in[0];
  const int* h_item_idx = (const int*)d_in[1];
  const float* h_item_val = (const float*)d_in[2];
  const int* h_user_idx = (const int*)d_in[3];
  const float* h_user_val = (const float*)d_in[4];
  const float* user_emb = (const float*)d_in[5];
  const float* w0 = (const float*)d_in[6];
  const float* w1 = (const float*)d_in[7];
  const float* b0 = (const float*)d_in[8];
  const float* b1 = (const float*)d_in[9];
  const float* att = (const float*)d_in[10];
  const float* att_m = (const float*)d_in[11];

  float* out = (float*)d_out;
  float* out_Lcas = out;                       // B*L*D
  float* out_cas = out + (size_t)BB * LL * D;  // B*L*D

  const size_t ND = (size_t)N_NODES * D;  // 6.4M elements
  char* ws = (char*)d_ws;
  float* e22 = (float*)ws; ws += ND * 4;
  float* e32 = (float*)ws; ws += ND * 4;
  ushort_t* h20 = (ushort_t*)ws; ws += ND * 2;
  ushort_t* h30 = (ushort_t*)ws; ws += ND * 2;
  ushort_t* h21 = (ushort_t*)ws; ws += ND * 2;
  ushort_t* h31 = (ushort_t*)ws; ws += ND * 2;
  uint2* binned = (uint2*)ws; ws += (size_t)NBUCK * CAP * 8;  // 28.8 MB
  uint32_t* gcursor = (uint32_t*)ws; ws += (size_t)((NBUCK + 63) & ~63) * 4;
  uint32_t* bitmap = (uint32_t*)ws; ws += (size_t)BM_WORDS * 4;
  uint32_t* grow_start = (uint32_t*)ws; ws += (size_t)N_NODES * 4;
  uint32_t* grow_cnt = (uint32_t*)ws; ws += (size_t)N_NODES * 4;
  int* list = (int*)ws; ws += (size_t)(BB * LL) * 4;
  int* nlist = (int*)ws; ws += 64;

  const int* item_dst = h_item_idx;
  const int* item_src = h_item_idx + NNZ;
  const int* user_dst = h_user_idx;
  const int* user_src = h_user_idx + NNZ;

  const int BIN_BLOCKS = (NNZ + BCHUNK - 1) / BCHUNK;  // 782

  // bitmap + compact list of rows actually needed by the output gather
  hipMemsetAsync(bitmap, 0, (size_t)BM_WORDS * 4, stream);
  hipMemsetAsync(nlist, 0, 64, stream);
  mark_kernel<<<(BB * LL + 255) / 256, 256, 0, stream>>>(input, bitmap, list, nlist);

  // gate (bf16-only output, packed-W LDS, 4 rows/wave)
  gate_kernel<<<1024, 256, 0, stream>>>(user_emb, w0, w1, b0, b1, h20, h30);

  // ---- item graph: bin -> sort+spmm layer1 (bf16 gather) -> list spmm layer2
  init_cursor_kernel<<<(NBUCK + 255) / 256, 256, 0, stream>>>(gcursor);
  bin_kernel<<<BIN_BLOCKS, 1024, 0, stream>>>(item_dst, item_src, h_item_val, gcursor, binned);
  sortspmm_kernel<<<NBUCK, 512, 0, stream>>>(gcursor, binned, h20, h21, grow_start, grow_cnt);
  listspmm_kernel<<<3200, 256, 0, stream>>>(grow_start, grow_cnt, binned, h21, e22, list, nlist);

  // ---- user graph
  init_cursor_kernel<<<(NBUCK + 255) / 256, 256, 0, stream>>>(gcursor);
  bin_kernel<<<BIN_BLOCKS, 1024, 0, stream>>>(user_dst, user_src, h_user_val, gcursor, binned);
  sortspmm_kernel<<<NBUCK, 512, 0, stream>>>(gcursor, binned, h30, h31, grow_start, grow_cnt);
  listspmm_kernel<<<3200, 256, 0, stream>>>(grow_start, grow_cnt, binned, h31, e32, list, nlist);

  // ---- fused acc / l2norm / attention-mix / sequence attention
  final_kernel<<<BB, 256, 0, stream>>>(input, h20, h21, e22, h30, h31, e32,
                                       att, att_m, out_Lcas, out_cas);
}